// Round 7
// baseline (494.482 us; speedup 1.0000x reference)
//
#include <hip/hip_runtime.h>
#include <hip/hip_bf16.h>
#include <math.h>

typedef __hip_bfloat16 bf16;
typedef __attribute__((ext_vector_type(8))) short short8_t;
typedef __attribute__((ext_vector_type(4))) short short4_t;
typedef __attribute__((ext_vector_type(4))) float f32x4_t;

#define EPSV 1e-5f
#define BNSC 0.99999500003749968f  // 1/sqrt(1+1e-5)

__device__ __forceinline__ float bf2f(bf16 v){ return __bfloat162float(v); }
__device__ __forceinline__ bf16 f2bf(float v){ return __float2bfloat16(v); }

__device__ __forceinline__ float blk_sum(float v, float* sm){
  int tid = threadIdx.x;
  #pragma unroll
  for(int o=32;o>0;o>>=1) v += __shfl_down(v, o, 64);
  if((tid&63)==0) sm[tid>>6] = v;
  __syncthreads();
  float s = 0.f;
  int nw = blockDim.x>>6;
  for(int i=0;i<nw;i++) s += sm[i];
  __syncthreads();
  return s;
}

__device__ __forceinline__ float softplusf(float x){
  return (x > 20.f) ? x : __logf(1.f + __expf(x));
}
__device__ __forceinline__ float siluf(float x){
  return x / (1.f + __expf(-x));
}

// one-shot prep: bf16 converts (incl xproj) + proj transpose + zero stat accumulators
__global__ void prep_weights(const float* __restrict__ in_w, const float* __restrict__ out_w,
                             const float* __restrict__ pw_w, const float* __restrict__ dpw_w,
                             const float* __restrict__ proj_w, const float* __restrict__ xproj_w,
                             bf16* __restrict__ Winb, bf16* __restrict__ Woutb,
                             bf16* __restrict__ Wub, bf16* __restrict__ Wdb,
                             bf16* __restrict__ Wxpb, float* __restrict__ PT,
                             float* __restrict__ gacc){
  int idx = blockIdx.x*256 + threadIdx.x;      // < 1,097,728
  if(idx < 6656) gacc[idx] = 0.f;              // gsum1/gssq1 + t1s/t1q/t1x
  if(idx < 524288){ Winb[idx] = f2bf(in_w[idx]); return; }
  if(idx < 786432){ int i=idx-524288; Woutb[i] = f2bf(out_w[i]); return; }
  if(idx < 851968){ int i=idx-786432; Wub[i] = f2bf(pw_w[i]); return; }
  if(idx < 917504){ int i=idx-851968; Wdb[i] = f2bf(dpw_w[i]); return; }
  if(idx < 1048576){
    int k = idx - 917504;                      // < 131072
    int i = k >> 9, j = k & 511;
    PT[j*256 + i] = proj_w[k];
    return;
  }
  int i = idx - 1048576;                       // < 49152
  Wxpb[i] = f2bf(xproj_w[i]);
}

// R1 (256 threads): load x slice coalesced; wave0 = col reduce, wave1 = row reduce
// + per-(b,c) sum/ssq of x for the fused GN3 composition
__global__ __launch_bounds__(256)
void r1_reduce_pe(const float* __restrict__ x, const float* __restrict__ pe,
                  float* __restrict__ pmax, float* __restrict__ pmin,
                  float* __restrict__ xs, float* __restrict__ xq){
  __shared__ float tile[64*65];
  __shared__ float rs_[4], rq_[4];
  int bc = blockIdx.x;          // b*256 + c
  int b = bc >> 8, c = bc & 255;
  const float* xp = x + ((size_t)bc << 12);
  float s = 0.f, q = 0.f;
  for(int i=threadIdx.x; i<4096; i+=256){
    float v = xp[i];
    tile[(i>>6)*65 + (i&63)] = v;
    s += v; q += v*v;
  }
  #pragma unroll
  for(int o=32;o>0;o>>=1){ s += __shfl_down(s, o, 64); q += __shfl_down(q, o, 64); }
  int wv = threadIdx.x >> 6, t = threadIdx.x & 63;
  if(t == 0){ rs_[wv] = s; rq_[wv] = q; }
  __syncthreads();
  if(threadIdx.x == 0){
    xs[bc] = rs_[0]+rs_[1]+rs_[2]+rs_[3];
    xq[bc] = rq_[0]+rq_[1]+rq_[2]+rq_[3];
  }
  if(wv >= 2) return;
  float coords = fmaxf((t + 0.5f)*0.25f - 0.5f, 0.f);
  int i0 = (int)floorf(coords);
  int i1 = min(i0+1, 15);
  float wg = coords - (float)i0;
  float pos = pe[c*16+i0]*(1.f-wg) + pe[c*16+i1]*wg;
  if(wv == 0){
    float cmx=-3.4e38f, cmn=3.4e38f; int cax=0, can=0;
    for(int h=0;h<64;h++){
      float v = tile[h*65 + t];
      if(v > cmx){ cmx=v; cax=h; }
      if(v < cmn){ cmn=v; can=h; }
    }
    size_t base_col = ((size_t)b*128 + t)*256 + c;
    pmax[base_col] = cmx + pos + (float)cax;
    pmin[base_col] = cmn + pos + (float)can;
  } else {
    float rmx=-3.4e38f, rmn=3.4e38f; int rax=0, ran=0;
    for(int w=0;w<64;w++){
      float v = tile[t*65 + w];
      if(v > rmx){ rmx=v; rax=w; }
      if(v < rmn){ rmn=v; ran=w; }
    }
    size_t base_row = ((size_t)b*128 + 64 + t)*256 + c;
    pmax[base_row] = rmx + pos + (float)rax;
    pmin[base_row] = rmn + pos + (float)ran;
  }
}

// paired LN over 256: rows<1024 -> A, else B; writes f32 back + bf16 copy
__global__ void ln_rows2(float* __restrict__ bufA, float* __restrict__ bufB,
                         const float* __restrict__ g, const float* __restrict__ bb,
                         bf16* __restrict__ boutA, bf16* __restrict__ boutB){
  __shared__ float sm[8];
  int row = blockIdx.x, t = threadIdx.x;
  float* buf; bf16* bout;
  if(row < 1024){ buf = bufA; bout = boutA; }
  else { buf = bufB; bout = boutB; row -= 1024; }
  float v = buf[(size_t)row*256 + t];
  float m = blk_sum(v, sm) * (1.f/256.f);
  float dv = v - m;
  float var = blk_sum(dv*dv, sm) * (1.f/256.f);
  float r = dv * rsqrtf(var + EPSV) * g[t] + bb[t];
  buf[(size_t)row*256 + t] = r;
  if(bout) bout[(size_t)row*256 + t] = f2bf(r);
}

// M1 (MFMA): xz[rb][l][i] = sum_c u_bf(b,l_eff,c) * in_w_bf[d][i][c]
__global__ __launch_bounds__(256,2)
void m1_mfma(const bf16* __restrict__ ubmax, const bf16* __restrict__ ubmin,
             const bf16* __restrict__ Win, float* __restrict__ xz){
  __shared__ bf16 att[64*264];
  int bx = blockIdx.x;
  int it = bx & 3, lt = (bx>>2)&1, b = (bx>>3)&7, r = bx>>6;
  int d = r & 1;
  const bf16* u = (r < 2) ? ubmax : ubmin;
  int flip = r & 1;
  int t = threadIdx.x;
  {
    int pr = t>>5, cc = (t&31)*8;
    #pragma unroll
    for(int i=0;i<8;i++){
      int p = pr + i*8;
      int l = lt*64 + p;
      int le = flip ? (127 - l) : l;
      short8_t v = *(const short8_t*)((const short*)u + ((size_t)(b*128 + le))*256 + cc);
      *(short8_t*)&att[p*264 + cc] = v;
    }
  }
  __syncthreads();
  int wv = t>>6, lane = t&63, quad = lane>>4, l16 = lane&15;
  int m0 = wv*64;
  f32x4_t acc[4][4];
  #pragma unroll
  for(int ms=0;ms<4;ms++)
    #pragma unroll
    for(int ns=0;ns<4;ns++) acc[ms][ns] = (f32x4_t){0.f,0.f,0.f,0.f};
  const short* wbase = (const short*)Win + ((size_t)d*1024 + it*256)*256;
  for(int k0=0;k0<256;k0+=32){
    short8_t afr[4], bfr[4];
    #pragma unroll
    for(int ms=0;ms<4;ms++)
      afr[ms] = *(const short8_t*)(wbase + (size_t)(m0 + ms*16 + l16)*256 + k0 + quad*8);
    #pragma unroll
    for(int ns=0;ns<4;ns++)
      bfr[ns] = *(const short8_t*)&att[(ns*16 + l16)*264 + k0 + quad*8];
    #pragma unroll
    for(int ms=0;ms<4;ms++)
      #pragma unroll
      for(int ns=0;ns<4;ns++)
        acc[ms][ns] = __builtin_amdgcn_mfma_f32_16x16x32_bf16(afr[ms], bfr[ns], acc[ms][ns], 0,0,0);
  }
  int rb = r*8 + b;
  #pragma unroll
  for(int ns=0;ns<4;ns++){
    int l = lt*64 + ns*16 + l16;
    float* dst = xz + ((size_t)rb*128 + l)*1024 + it*256;
    #pragma unroll
    for(int ms=0;ms<4;ms++){
      int i = m0 + ms*16 + quad*4;
      *(f32x4_t*)(dst + i) = acc[ms][ns];
    }
  }
}

// M2: conv (D_CONV=4 causal) + silu, streaming f32x4; writes xc (f32) + xcb (bf16)
__global__ __launch_bounds__(256)
void m2_conv(const float* __restrict__ xz, const float* __restrict__ cw,
             const float* __restrict__ cb, float* __restrict__ xc,
             bf16* __restrict__ xcb){
  int i4 = blockIdx.x*256 + threadIdx.x;   // < 524288
  int idx = i4 << 2;                        // element in [4096][512]
  int row = idx >> 9, dd = idx & 511;
  int gl = row & 127;
  int d = (row >> 10) & 1;
  const float* src = xz + (size_t)row*1024 + dd;
  const float* cwp = cw + (size_t)(d*512 + dd)*4;
  f32x4_t w0 = *(const f32x4_t*)(cwp);      // weights for dd+0 (k=0..3)
  f32x4_t w1 = *(const f32x4_t*)(cwp+4);
  f32x4_t w2 = *(const f32x4_t*)(cwp+8);
  f32x4_t w3 = *(const f32x4_t*)(cwp+12);
  f32x4_t bias = *(const f32x4_t*)(cb + d*512 + dd);
  f32x4_t z4 = (f32x4_t){0.f,0.f,0.f,0.f};
  f32x4_t t3 = *(const f32x4_t*)(src);
  f32x4_t t2 = (gl>=1) ? *(const f32x4_t*)(src-1024) : z4;
  f32x4_t t1 = (gl>=2) ? *(const f32x4_t*)(src-2048) : z4;
  f32x4_t t0 = (gl>=3) ? *(const f32x4_t*)(src-3072) : z4;
  f32x4_t o;
  o[0] = bias[0] + t0[0]*w0[0] + t1[0]*w0[1] + t2[0]*w0[2] + t3[0]*w0[3];
  o[1] = bias[1] + t0[1]*w1[0] + t1[1]*w1[1] + t2[1]*w1[2] + t3[1]*w1[3];
  o[2] = bias[2] + t0[2]*w2[0] + t1[2]*w2[1] + t2[2]*w2[2] + t3[2]*w2[3];
  o[3] = bias[3] + t0[3]*w3[0] + t1[3]*w3[1] + t2[3]*w3[2] + t3[3]*w3[3];
  alignas(8) bf16 ob[4];
  #pragma unroll
  for(int r=0;r<4;r++){ o[r] = siluf(o[r]); ob[r] = f2bf(o[r]); }
  *(f32x4_t*)(xc + idx) = o;
  *(short4_t*)((short*)xcb + idx) = *(const short4_t*)ob;
}

// M3 (MFMA): dbl[4096][48] = xcb[4096][512] x Wxpb[48][512]^T. 64 blocks x 4 waves.
__global__ __launch_bounds__(256)
void m3_xproj(const bf16* __restrict__ xcb, const bf16* __restrict__ Wxpb,
              float* __restrict__ dbl){
  int r0 = blockIdx.x * 64;
  int d = (r0 >> 10) & 1;
  int t = threadIdx.x;
  int wv = t>>6, lane = t&63, quad = lane>>4, l16 = lane&15;
  int rowl = wv*16 + l16;
  const short* bbase = (const short*)xcb + (size_t)(r0 + rowl)*512;
  const short* abase = (const short*)Wxpb + (size_t)d*48*512;
  f32x4_t acc[3];
  #pragma unroll
  for(int ms=0;ms<3;ms++) acc[ms] = (f32x4_t){0.f,0.f,0.f,0.f};
  #pragma unroll 4
  for(int k0=0;k0<512;k0+=32){
    short8_t bfr = *(const short8_t*)(bbase + k0 + quad*8);
    short8_t afr[3];
    #pragma unroll
    for(int ms=0;ms<3;ms++)
      afr[ms] = *(const short8_t*)(abase + (size_t)(ms*16 + l16)*512 + k0 + quad*8);
    #pragma unroll
    for(int ms=0;ms<3;ms++)
      acc[ms] = __builtin_amdgcn_mfma_f32_16x16x32_bf16(afr[ms], bfr, acc[ms], 0,0,0);
  }
  float* dst = dbl + (size_t)(r0 + rowl)*48;
  #pragma unroll
  for(int ms=0;ms<3;ms++)
    *(f32x4_t*)(dst + ms*16 + quad*4) = acc[ms];
}

// M4: dt = softplus(dbl[:, :16] . dtw^T + bias), streaming f32x4
__global__ __launch_bounds__(256)
void m4_dt(const float* __restrict__ dbl, const float* __restrict__ dtw,
           const float* __restrict__ dtbias, float* __restrict__ dt){
  int i4 = blockIdx.x*256 + threadIdx.x;   // < 524288
  int idx = i4 << 2;
  int row = idx >> 9, dd = idx & 511;
  int d = (row >> 10) & 1;
  const float* dr = dbl + (size_t)row*48;
  f32x4_t dr0 = *(const f32x4_t*)(dr);
  f32x4_t dr1 = *(const f32x4_t*)(dr+4);
  f32x4_t dr2 = *(const f32x4_t*)(dr+8);
  f32x4_t dr3 = *(const f32x4_t*)(dr+12);
  f32x4_t bias = *(const f32x4_t*)(dtbias + d*512 + dd);
  f32x4_t o;
  #pragma unroll
  for(int j=0;j<4;j++){
    const float* wp = dtw + (size_t)(d*512 + dd + j)*16;
    f32x4_t w0 = *(const f32x4_t*)(wp);
    f32x4_t w1 = *(const f32x4_t*)(wp+4);
    f32x4_t w2 = *(const f32x4_t*)(wp+8);
    f32x4_t w3 = *(const f32x4_t*)(wp+12);
    float s = bias[j];
    s += dr0[0]*w0[0] + dr0[1]*w0[1] + dr0[2]*w0[2] + dr0[3]*w0[3];
    s += dr1[0]*w1[0] + dr1[1]*w1[1] + dr1[2]*w1[2] + dr1[3]*w1[3];
    s += dr2[0]*w2[0] + dr2[1]*w2[1] + dr2[2]*w2[2] + dr2[3]*w2[3];
    s += dr3[0]*w3[0] + dr3[1]*w3[1] + dr3[2]*w3[2] + dr3[3]*w3[3];
    o[j] = softplusf(s);
  }
  *(f32x4_t*)(dt + idx) = o;
}

// M5a: chunked scan pass A
__global__ void m5_passA(const float* __restrict__ dt, const float* __restrict__ xc,
                         const float* __restrict__ dbl, const float* __restrict__ Alog,
                         float* __restrict__ P, float* __restrict__ Hl){
  int bx = blockIdx.x;
  int seg = bx & 7, half = (bx>>3)&1, rb = bx>>4;
  int dd = half*256 + threadIdx.x;
  int d = (rb>>3)&1;
  float A[16], h[16], pr[16];
  #pragma unroll
  for(int s=0;s<16;s++){
    A[s] = -__expf(Alog[(size_t)(d*512 + dd)*16 + s]);
    h[s] = 0.f; pr[s] = 1.f;
  }
  int l0 = seg*16;
  for(int l=l0;l<l0+16;l++){
    size_t row = (size_t)rb*128 + l;
    float dtv = dt[row*512 + dd];
    float xcv = xc[row*512 + dd];
    float bx_ = dtv*xcv;
    const float* dr = dbl + row*48;
    #pragma unroll
    for(int s=0;s<16;s++){
      float dA = __expf(dtv*A[s]);
      pr[s] *= dA;
      h[s] = dA*h[s] + bx_*dr[16+s];
    }
  }
  size_t o = ((size_t)(rb*8 + seg)*512 + dd)*16;
  #pragma unroll
  for(int s=0;s<16;s+=4){
    *(f32x4_t*)(P  + o + s) = (f32x4_t){pr[s],pr[s+1],pr[s+2],pr[s+3]};
    *(f32x4_t*)(Hl + o + s) = (f32x4_t){h[s],h[s+1],h[s+2],h[s+3]};
  }
}

// M5b: combine prefix, re-scan, emit y
__global__ void m5_passB(const float* __restrict__ dt, const float* __restrict__ xc,
                         const float* __restrict__ dbl, const float* __restrict__ xz,
                         const float* __restrict__ Alog, const float* __restrict__ Dp,
                         const float* __restrict__ P, const float* __restrict__ Hl,
                         bf16* __restrict__ ybb){
  int bx = blockIdx.x;
  int seg = bx & 7, half = (bx>>3)&1, rb = bx>>4;
  int dd = half*256 + threadIdx.x;
  int d = (rb>>3)&1;
  float A[16], h[16];
  #pragma unroll
  for(int s=0;s<16;s++){
    A[s] = -__expf(Alog[(size_t)(d*512 + dd)*16 + s]);
    h[s] = 0.f;
  }
  for(int j=0;j<seg;j++){
    size_t o = ((size_t)(rb*8 + j)*512 + dd)*16;
    #pragma unroll
    for(int s=0;s<16;s+=4){
      f32x4_t pv = *(const f32x4_t*)(P + o + s);
      f32x4_t hv = *(const f32x4_t*)(Hl + o + s);
      h[s]   = pv[0]*h[s]   + hv[0];
      h[s+1] = pv[1]*h[s+1] + hv[1];
      h[s+2] = pv[2]*h[s+2] + hv[2];
      h[s+3] = pv[3]*h[s+3] + hv[3];
    }
  }
  float Dv = Dp[d*512 + dd];
  int l0 = seg*16;
  for(int l=l0;l<l0+16;l++){
    size_t row = (size_t)rb*128 + l;
    float dtv = dt[row*512 + dd];
    float xcv = xc[row*512 + dd];
    float zgv = xz[row*1024 + 512 + dd];
    const float* dr = dbl + row*48;
    float bx_ = dtv*xcv;
    float y = 0.f;
    #pragma unroll
    for(int s=0;s<16;s++){
      h[s] = __expf(dtv*A[s])*h[s] + bx_*dr[16+s];
      y += h[s]*dr[32+s];
    }
    ybb[row*512 + dd] = f2bf((y + xcv*Dv) * siluf(zgv));
  }
}

// M6 (MFMA) + fused row-LN
__global__ __launch_bounds__(256,2)
void m6_mfma(const bf16* __restrict__ ybb, const bf16* __restrict__ Wout,
             const float* __restrict__ lng, const float* __restrict__ lnb,
             float* __restrict__ mo){
  __shared__ char smem[64*264*4];
  bf16* ybt = (bf16*)smem;
  float* fbuf = (float*)smem;
  int bx = blockIdx.x;
  int lt = bx & 1, b = (bx>>1)&7, r = bx>>4;
  int d = r & 1, rb = r*8 + b;
  size_t rowbase = (size_t)rb*128 + lt*64;
  int t = threadIdx.x;
  for(int i=t;i<4096;i+=256){
    int row = i>>6, c8 = (i&63)*8;
    short8_t v = *(const short8_t*)((const short*)ybb + (rowbase + row)*512 + c8);
    *(short8_t*)&ybt[row*520 + c8] = v;
  }
  __syncthreads();
  int wv = t>>6, lane = t&63, quad = lane>>4, l16 = lane&15;
  int m0 = wv*64;
  f32x4_t acc[4][4];
  #pragma unroll
  for(int ms=0;ms<4;ms++)
    #pragma unroll
    for(int ns=0;ns<4;ns++) acc[ms][ns] = (f32x4_t){0.f,0.f,0.f,0.f};
  const short* wbase = (const short*)Wout + (size_t)d*256*512;
  for(int k0=0;k0<512;k0+=32){
    short8_t afr[4], bfr[4];
    #pragma unroll
    for(int ms=0;ms<4;ms++)
      afr[ms] = *(const short8_t*)(wbase + (size_t)(m0 + ms*16 + l16)*512 + k0 + quad*8);
    #pragma unroll
    for(int ns=0;ns<4;ns++)
      bfr[ns] = *(const short8_t*)&ybt[(ns*16 + l16)*520 + k0 + quad*8];
    #pragma unroll
    for(int ms=0;ms<4;ms++)
      #pragma unroll
      for(int ns=0;ns<4;ns++)
        acc[ms][ns] = __builtin_amdgcn_mfma_f32_16x16x32_bf16(afr[ms], bfr[ns], acc[ms][ns], 0,0,0);
  }
  __syncthreads();
  #pragma unroll
  for(int ns=0;ns<4;ns++){
    int row = ns*16 + l16;
    #pragma unroll
    for(int ms=0;ms<4;ms++){
      int o = m0 + ms*16 + quad*4;
      *(f32x4_t*)(fbuf + row*264 + o) = acc[ms][ns];
    }
  }
  __syncthreads();
  {
    int row = t >> 2, part = t & 3;
    const float* fr = fbuf + row*264;
    float s = 0.f;
    #pragma unroll 8
    for(int j=0;j<64;j++){
      int col = part*64 + ((j + part*16) & 63);
      s += fr[col];
    }
    s += __shfl_xor(s, 1, 64);
    s += __shfl_xor(s, 2, 64);
    float m = s * (1.f/256.f);
    float q = 0.f;
    #pragma unroll 8
    for(int j=0;j<64;j++){
      int col = part*64 + ((j + part*16) & 63);
      float dv = fr[col] - m;
      q += dv*dv;
    }
    q += __shfl_xor(q, 1, 64);
    q += __shfl_xor(q, 2, 64);
    float rs = rsqrtf(q*(1.f/256.f) + EPSV);
    float* dst = mo + (rowbase + row)*256;
    for(int j=0;j<64;j++){
      int col = part*64 + j;
      dst[col] = (fr[col] - m)*rs*lng[col] + lnb[col];
    }
  }
}

// M7 + fused row-LN on outputs
__global__ void m7_proj(const float* __restrict__ mo, const float* __restrict__ PT,
                        const float* __restrict__ pb, const float* __restrict__ lng,
                        const float* __restrict__ lnb, float* __restrict__ resm,
                        float* __restrict__ resn){
  __shared__ float ct[16*512];
  __shared__ float fbuf[16*264];
  int bx = blockIdx.x;
  int tt = bx >> 6, rem = bx & 63, b = rem >> 3, lt = rem & 7;
  int fr_ = tt*2, br = tt*2 + 1;
  for(int i=threadIdx.x;i<16*512;i+=256){
    int lr = i >> 9, k = i & 511;
    int l = lt*16 + lr;
    ct[i] = (k < 256)
      ? mo[(((size_t)(fr_*8+b)*128) + l)*256 + k]
      : mo[(((size_t)(br*8+b)*128) + (127-l))*256 + (k-256)];
  }
  __syncthreads();
  float acc[16];
  #pragma unroll
  for(int q=0;q<16;q++) acc[q] = 0.f;
  int t = threadIdx.x;
  for(int k=0;k<512;k++){
    float pv = PT[(size_t)k*256 + t];
    #pragma unroll
    for(int q=0;q<16;q++) acc[q] += pv * ct[(q<<9) + k];
  }
  float bias = pb[t];
  #pragma unroll
  for(int q=0;q<16;q++) fbuf[q*264 + t] = acc[q] + bias;
  __syncthreads();
  float* dstbuf = tt ? resn : resm;
  if(t < 64){
    int row = t >> 2, part = t & 3;
    const float* fr = fbuf + row*264;
    float s = 0.f;
    for(int j=0;j<64;j++){
      int col = part*64 + ((j + part*16) & 63);
      s += fr[col];
    }
    s += __shfl_xor(s, 1, 64);
    s += __shfl_xor(s, 2, 64);
    float m = s * (1.f/256.f);
    float q = 0.f;
    for(int j=0;j<64;j++){
      int col = part*64 + ((j + part*16) & 63);
      float dv = fr[col] - m;
      q += dv*dv;
    }
    q += __shfl_xor(q, 1, 64);
    q += __shfl_xor(q, 2, 64);
    float rs = rsqrtf(q*(1.f/256.f) + EPSV);
    float* dst = dstbuf + ((size_t)b*128 + lt*16 + row)*256;
    for(int j=0;j<64;j++){
      int col = part*64 + j;
      dst[col] = (fr[col] - m)*rs*lng[col] + lnb[col];
    }
  }
}

// K1: stride-2 transposed depthwise 3x3 + BN + ReLU -> zT (pixel-major bf16)
__global__ __launch_bounds__(256)
void k1_deconv_T(const float* __restrict__ x, const float* __restrict__ wdw,
                 const float* __restrict__ g1, const float* __restrict__ b1,
                 bf16* __restrict__ zT){
  __shared__ float in[2*64*33];
  __shared__ bf16 ot[64*80];
  int bx = blockIdx.x;
  int cb = bx & 3, half = (bx>>2)&1, h = (bx>>3)&127, b = bx>>10;
  int c0 = cb*64, w0 = half*64, iw0 = w0>>1;
  int h_odd = h & 1;
  int ihA = h_odd ? (h-1)>>1 : h>>1;
  int ihB = (h+1)>>1;
  bool hasB = h_odd && (ihB < 64);
  for(int i = threadIdx.x; i < 4224; i += 256){
    int row = i / 2112;
    int rem = i - row*2112;
    int c = rem / 33;
    int iw = rem - c*33;
    int ihl = row ? ihB : ihA;
    bool valid = (iw0 + iw < 64) && (row == 0 || hasB);
    in[i] = valid ? x[(((size_t)b*256 + c0 + c)<<12) + (ihl<<6) + iw0 + iw] : 0.f;
  }
  __syncthreads();
  int c = threadIdx.x & 63, g = threadIdx.x >> 6;
  const float* wp = wdw + (c0+c)*9;
  int khA3 = h_odd ? 6 : 3;
  float wA0 = wp[khA3], wA1 = wp[khA3+1], wA2 = wp[khA3+2];
  float wB0 = wp[0],    wB1 = wp[1],      wB2 = wp[2];
  float scale = g1[c0+c]*BNSC, bias = b1[c0+c];
  const float* inA = in + c*33;
  const float* inB = in + 2112 + c*33;
  #pragma unroll
  for(int i=0;i<16;i++){
    int wi = g*16 + i;
    float s;
    if(!(i&1)){
      int iw = wi>>1;
      s = inA[iw]*wA1 + inB[iw]*wB1;
    } else {
      int iwa = (wi-1)>>1, iwb = (wi+1)>>1;
      s = inA[iwa]*wA2 + inA[iwb]*wA0 + inB[iwa]*wB2 + inB[iwb]*wB0;
    }
    ot[wi*80 + c] = f2bf(fmaxf(s*scale + bias, 0.f));
  }
  __syncthreads();
  int rr = threadIdx.x >> 3;
  int co = (threadIdx.x & 7) * 8;
  size_t obase = (((size_t)b*16384) + (size_t)h*128 + w0)*256 + c0;
  #pragma unroll
  for(int pass=0; pass<2; pass++){
    int wi = rr + pass*32;
    short8_t v = *(const short8_t*)&ot[wi*80 + co];
    *(short8_t*)((short*)zT + obase + (size_t)wi*256 + co) = v;
  }
}

// K2 v4 (MFMA): 64-px tile, NO input LDS staging (B-fragments read direct from
// L2-hot zT), fused GN1 stats, compact subsampled output via small ot buffer.
// grid (256, 8); ~4-5 blocks/CU.
__global__ __launch_bounds__(256,4)
void k2_mfma(const bf16* __restrict__ zT, const bf16* __restrict__ Wub,
             const float* __restrict__ g2, const float* __restrict__ b2,
             const float* __restrict__ resm, const float* __restrict__ resn,
             bf16* __restrict__ resS, float* __restrict__ gsum1, float* __restrict__ gssq1){
  __shared__ bf16 ot[32*264];
  __shared__ float rm_s[256];
  __shared__ float gn_s[32], gn_q[32];
  int b = blockIdx.y;
  int p0 = blockIdx.x*64;          // 64-pixel tile (half of row h)
  int h = p0 >> 7;
  int w0 = p0 & 127;               // 0 or 64
  int t = threadIdx.x;
  if(t < 32){ gn_s[t] = 0.f; gn_q[t] = 0.f; }
  if(t >= 64 && t < 128){
    int tt = t - 64;
    *(f32x4_t*)&rm_s[tt*4] = *(const f32x4_t*)(resm + ((size_t)b*128 + h)*256 + tt*4);
  }
  int wv = t>>6, lane = t&63, quad = lane>>4, l16 = lane&15;
  int m0 = wv*64;
  f32x4_t acc[4][4];
  #pragma unroll
  for(int ms=0;ms<4;ms++)
    #pragma unroll
    for(int ns=0;ns<4;ns++) acc[ms][ns] = (f32x4_t){0.f,0.f,0.f,0.f};
  const short* wp = (const short*)Wub + (size_t)(m0 + l16)*256 + quad*8;
  const short* zsrc = (const short*)zT + (((size_t)b*16384 + p0)*256);
  short8_t afr[4];
  #pragma unroll
  for(int ms=0;ms<4;ms++) afr[ms] = *(const short8_t*)(wp + (size_t)ms*16*256);
  for(int k0=0;k0<256;k0+=32){
    short8_t anext[4];
    if(k0 + 32 < 256){
      #pragma unroll
      for(int ms=0;ms<4;ms++)
        anext[ms] = *(const short8_t*)(wp + (size_t)ms*16*256 + k0 + 32);
    }
    short8_t bfr[4];
    #pragma unroll
    for(int ns=0;ns<4;ns++)
      bfr[ns] = *(const short8_t*)(zsrc + (size_t)(ns*16 + l16)*256 + k0 + quad*8);
    #pragma unroll
    for(int ms=0;ms<4;ms++)
      #pragma unroll
      for(int ns=0;ns<4;ns++)
        acc[ms][ns] = __builtin_amdgcn_mfma_f32_16x16x32_bf16(afr[ms], bfr[ns], acc[ms][ns], 0,0,0);
    #pragma unroll
    for(int ms=0;ms<4;ms++) afr[ms] = anext[ms];
  }
  __syncthreads();       // rm_s / gn zero-init visible to all
  bool h_even = ((h & 1) == 0);
  float sg[4], qg[4];
  #pragma unroll
  for(int ms=0;ms<4;ms++){ sg[ms]=0.f; qg[ms]=0.f; }
  #pragma unroll
  for(int ns=0;ns<4;ns++){
    int pl = ns*16 + l16;            // local pixel 0..63 ; global w = w0 + pl
    int w = w0 + pl;
    const float* rn = resn + ((size_t)b*128 + w)*256;
    bool store = h_even && ((pl & 1) == 0);
    #pragma unroll
    for(int ms=0;ms<4;ms++){
      int o = m0 + ms*16 + quad*4;
      f32x4_t a = acc[ms][ns];
      f32x4_t gv = *(const f32x4_t*)(g2+o);
      f32x4_t bv = *(const f32x4_t*)(b2+o);
      f32x4_t rmv = *(const f32x4_t*)&rm_s[o];
      f32x4_t rnv = *(const f32x4_t*)(rn+o);
      alignas(8) bf16 ov[4];
      #pragma unroll
      for(int r=0;r<4;r++){
        float zv = a[r]*(gv[r]*BNSC) + bv[r];
        zv = fminf(fmaxf(zv, 0.f), 6.f);
        float gate = fminf(fmaxf(rmv[r]+rnv[r]+3.f, 0.f), 6.f)*(1.f/6.f);
        float vo = zv*gate;
        ov[r] = f2bf(vo);
        sg[ms] += vo;
        qg[ms] += vo*vo;
      }
      if(store) *(short4_t*)&ot[(pl>>1)*264 + o] = *(const short4_t*)ov;
    }
  }
  // GN1 partial sums: reduce over l16 lanes (pixel axis), then LDS per-group accum
  #pragma unroll
  for(int ms=0;ms<4;ms++){
    float S = sg[ms], Q = qg[ms];
    S += __shfl_xor(S, 1, 64);  Q += __shfl_xor(Q, 1, 64);
    S += __shfl_xor(S, 2, 64);  Q += __shfl_xor(Q, 2, 64);
    S += __shfl_xor(S, 4, 64);  Q += __shfl_xor(Q, 4, 64);
    S += __shfl_xor(S, 8, 64);  Q += __shfl_xor(Q, 8, 64);
    if(l16 == 0){
      int o = m0 + ms*16 + quad*4;   // 4 consecutive channels, same group o>>3
      atomicAdd(&gn_s[o>>3], S);
      atomicAdd(&gn_q[o>>3], Q);
    }
  }
  __syncthreads();
  if(t < 32){
    atomicAdd(&gsum1[b*32 + t], gn_s[t]);
    atomicAdd(&gssq1[b*32 + t], gn_q[t]);
  }
  // stream out (even h only): 32 even-w pixels -> contiguous 16KB burst
  if(h_even){
    short* dst = (short*)resS + ((size_t)b*4096 + (h>>1)*64 + (w0>>1))*256;
    #pragma unroll
    for(int it=0; it<4; it++){
      int slot = t + it*256;          // 1024 slots (32 rows x 32)
      int row = slot >> 5;
      int co = (slot & 31)*8;
      short8_t v = *(const short8_t*)&ot[row*264 + co];
      *(short8_t*)(dst + (size_t)row*256 + co) = v;
    }
  }
}

// K4 v4 (MFMA): 64-px tile (grid 64x8 -> 512 blocks, ~4 blocks/CU), reads compact
// resS, inline GN1 finalize, per-channel (sum, ssq, cross-with-x) stats.
__global__ __launch_bounds__(256,4)
void k4_mfma(const bf16* __restrict__ resS, const bf16* __restrict__ Wdb,
             const float* __restrict__ gsum1, const float* __restrict__ gssq1,
             const float* __restrict__ gng, const float* __restrict__ gnb,
             const float* __restrict__ dbg, const float* __restrict__ dbb,
             const float* __restrict__ x, float* __restrict__ t1,
             float* __restrict__ t1s, float* __restrict__ t1q, float* __restrict__ t1x){
  __shared__ bf16 at[64*264];
  __shared__ float sc[256], sb[256];
  __shared__ float stm[32], str[32];
  int b = blockIdx.y;
  int q0 = blockIdx.x*64;
  int t = threadIdx.x;
  if(t < 32){
    float m = gsum1[b*32+t] * (1.f/131072.f);
    float var = gssq1[b*32+t] * (1.f/131072.f) - m*m;
    stm[t] = m;
    str[t] = rsqrtf(var + EPSV);
  }
  __syncthreads();
  {
    int cch = t, g = cch>>3;
    float m = stm[g], rs = str[g];
    float s = rs*gng[cch];
    sc[cch] = s; sb[cch] = gnb[cch] - m*s;
  }
  __syncthreads();
  {
    int pr = t>>5;
    int cc = (t&31)*8;
    const short* src = (const short*)resS + ((size_t)b*4096 + q0)*256;
    #pragma unroll
    for(int i=0;i<8;i++){
      int q = pr + i*8;
      short8_t v = *(const short8_t*)(src + (size_t)q*256 + cc);
      const bf16* vv = (const bf16*)&v;
      alignas(16) bf16 ov[8];
      #pragma unroll
      for(int j=0;j<8;j++) ov[j] = f2bf(bf2f(vv[j])*sc[cc+j] + sb[cc+j]);
      *(short8_t*)&at[q*264 + cc] = *(const short8_t*)ov;
    }
  }
  __syncthreads();
  int wv = t>>6, lane = t&63, quad = lane>>4, l16 = lane&15;
  int n0 = wv*64;
  f32x4_t acc[4][4];
  #pragma unroll
  for(int ms=0;ms<4;ms++)
    #pragma unroll
    for(int ns=0;ns<4;ns++) acc[ms][ns] = (f32x4_t){0.f,0.f,0.f,0.f};
  const short* wp = (const short*)Wdb + (size_t)(n0 + l16)*256 + quad*8;
  short8_t bfr[4];
  #pragma unroll
  for(int ns=0;ns<4;ns++) bfr[ns] = *(const short8_t*)(wp + (size_t)ns*16*256);
  for(int k0=0;k0<256;k0+=32){
    short8_t bnext[4];
    if(k0 + 32 < 256){
      #pragma unroll
      for(int ns=0;ns<4;ns++)
        bnext[ns] = *(const short8_t*)(wp + (size_t)ns*16*256 + k0 + 32);
    }
    short8_t afr[4];
    #pragma unroll
    for(int ms=0;ms<4;ms++)
      afr[ms] = *(const short8_t*)&at[(ms*16 + l16)*264 + k0 + quad*8];
    #pragma unroll
    for(int ms=0;ms<4;ms++)
      #pragma unroll
      for(int ns=0;ns<4;ns++)
        acc[ms][ns] = __builtin_amdgcn_mfma_f32_16x16x32_bf16(afr[ms], bfr[ns], acc[ms][ns], 0,0,0);
    #pragma unroll
    for(int ns=0;ns<4;ns++) bfr[ns] = bnext[ns];
  }
  #pragma unroll
  for(int ns=0;ns<4;ns++){
    int o = n0 + ns*16 + l16;
    float s2 = dbg[o]*BNSC, bb2 = dbb[o];
    float* dst = t1 + (((size_t)b*256 + o) << 12);
    const float* xsrc = x + (((size_t)b*256 + o) << 12);
    float s_=0.f, q_=0.f, c_=0.f;
    #pragma unroll
    for(int ms=0;ms<4;ms++){
      int ps = q0 + ms*16 + quad*4;
      f32x4_t a = acc[ms][ns];
      f32x4_t xv = *(const f32x4_t*)(xsrc + ps);
      f32x4_t ov;
      #pragma unroll
      for(int r=0;r<4;r++){
        ov[r] = a[r]*s2 + bb2;
        s_ += ov[r];
        q_ += ov[r]*ov[r];
        c_ += ov[r]*xv[r];
      }
      *(f32x4_t*)(dst + ps) = ov;
    }
    // reduce over quads (pixel axis) only -> per-channel partials
    s_ += __shfl_xor(s_, 16, 64);
    q_ += __shfl_xor(q_, 16, 64);
    c_ += __shfl_xor(c_, 16, 64);
    s_ += __shfl_xor(s_, 32, 64);
    q_ += __shfl_xor(q_, 32, 64);
    c_ += __shfl_xor(c_, 32, 64);
    if(quad == 0){
      atomicAdd(&t1s[b*256 + o], s_);
      atomicAdd(&t1q[b*256 + o], q_);
      atomicAdd(&t1x[b*256 + o], c_);
    }
  }
}

// compose: per-(b,c) affine coefficients for out = A*t1 + B*x + C  (gn3(gn2(t1)+x))
__global__ void compose_gn(const float* __restrict__ t1s, const float* __restrict__ t1q,
                           const float* __restrict__ t1x, const float* __restrict__ xs,
                           const float* __restrict__ xq, const float* __restrict__ gng,
                           const float* __restrict__ gnb,
                           float* __restrict__ cA, float* __restrict__ cB, float* __restrict__ cC){
  int b = blockIdx.x, c = threadIdx.x;
  int i = b*256 + c;
  float ts = t1s[i], tq = t1q[i], tx = t1x[i];
  float sx = xs[i], qx = xq[i];
  // GN2 group stats (8 consecutive channels per group; lanes 8k..8k+7)
  float gs = ts, gq = tq;
  gs += __shfl_xor(gs,1,64); gq += __shfl_xor(gq,1,64);
  gs += __shfl_xor(gs,2,64); gq += __shfl_xor(gq,2,64);
  gs += __shfl_xor(gs,4,64); gq += __shfl_xor(gq,4,64);
  float m2 = gs*(1.f/32768.f);
  float v2 = gq*(1.f/32768.f) - m2*m2;
  float rs2 = rsqrtf(v2 + EPSV);
  float a  = rs2*gng[c];
  float bb = gnb[c] - m2*a;
  // u = a*t1 + bb + x ; per-channel stats of u
  float Su = a*ts + 4096.f*bb + sx;
  float Qu = a*a*tq + 4096.f*bb*bb + qx + 2.f*a*bb*ts + 2.f*a*tx + 2.f*bb*sx;
  float gSu = Su, gQu = Qu;
  gSu += __shfl_xor(gSu,1,64); gQu += __shfl_xor(gQu,1,64);
  gSu += __shfl_xor(gSu,2,64); gQu += __shfl_xor(gQu,2,64);
  gSu += __shfl_xor(gSu,4,64); gQu += __shfl_xor(gQu,4,64);
  float m3 = gSu*(1.f/32768.f);
  float v3 = gQu*(1.f/32768.f) - m3*m3;
  float rs3 = rsqrtf(v3 + EPSV);
  float s3 = rs3*gng[c];
  cA[i] = a*s3;
  cB[i] = s3;
  cC[i] = (bb - m3)*s3 + gnb[c];
}

// K8 v2 (float4): out = A*t1 + B*x + C   (replaces k6+k8)
__global__ void k8_gn_out(const float* __restrict__ t1, const float* __restrict__ x,
                          const float* __restrict__ cA, const float* __restrict__ cB,
                          const float* __restrict__ cC, float* __restrict__ out){
  int i4 = blockIdx.x*256 + threadIdx.x;
  int idx = i4 << 2;
  int c = (idx >> 12) & 255, b = idx >> 20;
  int i = b*256 + c;
  float A = cA[i], Bv = cB[i], C = cC[i];
  f32x4_t tv = *(const f32x4_t*)(t1 + idx);
  f32x4_t xv = *(const f32x4_t*)(x + idx);
  f32x4_t ov;
  #pragma unroll
  for(int r=0;r<4;r++) ov[r] = A*tv[r] + Bv*xv[r] + C;
  *(f32x4_t*)(out + idx) = ov;
}

extern "C" void kernel_launch(void* const* d_in, const int* in_sizes, int n_in,
                              void* d_out, int out_size, void* d_ws, size_t ws_size,
                              hipStream_t stream){
  const float* x      = (const float*)d_in[0];
  const float* pos    = (const float*)d_in[1];
  const float* ln_g   = (const float*)d_in[2];
  const float* ln_b   = (const float*)d_in[3];
  const float* in_w   = (const float*)d_in[4];
  const float* conv_w = (const float*)d_in[5];
  const float* conv_b = (const float*)d_in[6];
  const float* xproj  = (const float*)d_in[7];
  const float* dt_w   = (const float*)d_in[8];
  const float* dt_b   = (const float*)d_in[9];
  const float* A_log  = (const float*)d_in[10];
  const float* Dp     = (const float*)d_in[11];
  const float* out_w  = (const float*)d_in[12];
  const float* proj_w = (const float*)d_in[13];
  const float* proj_b = (const float*)d_in[14];
  const float* dw_w   = (const float*)d_in[15];
  const float* bn1g   = (const float*)d_in[16];
  const float* bn1b   = (const float*)d_in[17];
  const float* pw_w   = (const float*)d_in[18];
  const float* bn2g   = (const float*)d_in[19];
  const float* bn2b   = (const float*)d_in[20];
  const float* dpw_w  = (const float*)d_in[21];
  const float* dbng   = (const float*)d_in[22];
  const float* dbnb   = (const float*)d_in[23];
  const float* gng    = (const float*)d_in[24];
  const float* gnb    = (const float*)d_in[25];
  float* out = (float*)d_out;

  float* ws = (float*)d_ws;
  bf16*  resS = (bf16*)ws;                       // compact subsampled (b,4096,256), 16MB
  bf16*  zT   = (bf16*)(ws + 16777216);          // pixel-major (b,p,c), 64MB
  float* scanP = ws + 16777216;                  // overlay of zT region
  float* scanH = ws + 16777216 + 2097152;
  float* zone = ws + 33554432;
  float* xz   = zone;                            // 4,194,304
  float* xc   = xz  + 4194304;                   // 2,097,152
  float* dbl  = xc  + 2097152;                   //   196,608
  float* dtb  = dbl + 196608;                    // 2,097,152
  bf16*  ybb  = (bf16*)(dtb + 2097152);          // 1,048,576 f worth
  bf16*  xcb  = (bf16*)(dtb + 2097152 + 524288); // 1,048,576 f worth (2M bf16)
  float* t1   = zone;                            // overlay (first 8,388,608)
  float* mo   = zone + 9633792;                  // 1,048,576
  float* resm = mo   + 1048576;
  float* resn = resm + 262144;
  float* pmax = resn + 262144;
  float* pmin = pmax + 262144;
  float* PT   = pmin + 262144;
  bf16*  ubmax= (bf16*)(PT + 131072);
  bf16*  ubmin= (bf16*)(PT + 131072 + 131072);
  bf16*  Winb = (bf16*)(PT + 131072 + 262144);
  bf16*  Woutb= (bf16*)(PT + 131072 + 524288);
  bf16*  Wub  = (bf16*)(PT + 131072 + 655360);
  bf16*  Wdb  = (bf16*)(PT + 131072 + 688128);
  bf16*  Wxpb = (bf16*)(PT + 131072 + 720896);   // 49152 bf16 = 24576 floats
  float* gacc = PT + 131072 + 745472;
  float* gsum1 = gacc,        *gssq1 = gacc + 256;
  float* t1s = gacc + 512;
  float* t1q = gacc + 2560;
  float* t1x = gacc + 4608;
  float* xs  = gacc + 6656;
  float* xq  = gacc + 8704;
  float* cA  = gacc + 10752;
  float* cB  = gacc + 12800;
  float* cC  = gacc + 14848;

  prep_weights<<<4288,256,0,stream>>>(in_w, out_w, pw_w, dpw_w, proj_w, xproj,
                                      Winb, Woutb, Wub, Wdb, Wxpb, PT, gacc);

  r1_reduce_pe<<<2048,256,0,stream>>>(x, pos, pmax, pmin, xs, xq);
  ln_rows2<<<2048,256,0,stream>>>(pmax, pmin, ln_g, ln_b, ubmax, ubmin);

  m1_mfma<<<256,256,0,stream>>>(ubmax, ubmin, Winb, xz);
  m2_conv<<<2048,256,0,stream>>>(xz, conv_w, conv_b, xc, xcb);
  m3_xproj<<<64,256,0,stream>>>(xcb, Wxpb, dbl);
  m4_dt<<<2048,256,0,stream>>>(dbl, dt_w, dt_b, dtb);
  m5_passA<<<512,256,0,stream>>>(dtb, xc, dbl, A_log, scanP, scanH);
  m5_passB<<<512,256,0,stream>>>(dtb, xc, dbl, xz, A_log, Dp, scanP, scanH, ybb);
  m6_mfma<<<64,256,0,stream>>>(ybb, Woutb, ln_g, ln_b, mo);
  m7_proj<<<128,256,0,stream>>>(mo, PT, proj_b, ln_g, ln_b, resm, resn);

  k1_deconv_T<<<8192,256,0,stream>>>(x, dw_w, bn1g, bn1b, zT);
  k2_mfma<<<dim3(256,8),256,0,stream>>>(zT, Wub, bn2g, bn2b, resm, resn, resS,
                                        gsum1, gssq1);

  k4_mfma<<<dim3(64,8),256,0,stream>>>(resS, Wdb, gsum1, gssq1,
                                       gng, gnb, dbng, dbnb, x, t1, t1s, t1q, t1x);

  compose_gn<<<8,256,0,stream>>>(t1s, t1q, t1x, xs, xq, gng, gnb, cA, cB, cC);
  k8_gn_out<<<8192,256,0,stream>>>(t1, x, cA, cB, cC, out);
}

// Round 8
// 477.591 us; speedup vs baseline: 1.0354x; 1.0354x over previous
//
#include <hip/hip_runtime.h>
#include <hip/hip_bf16.h>
#include <math.h>

typedef __hip_bfloat16 bf16;
typedef __attribute__((ext_vector_type(8))) short short8_t;
typedef __attribute__((ext_vector_type(4))) short short4_t;
typedef __attribute__((ext_vector_type(4))) float f32x4_t;

#define EPSV 1e-5f
#define BNSC 0.99999500003749968f  // 1/sqrt(1+1e-5)

__device__ __forceinline__ float bf2f(bf16 v){ return __bfloat162float(v); }
__device__ __forceinline__ bf16 f2bf(float v){ return __float2bfloat16(v); }

__device__ __forceinline__ float blk_sum(float v, float* sm){
  int tid = threadIdx.x;
  #pragma unroll
  for(int o=32;o>0;o>>=1) v += __shfl_down(v, o, 64);
  if((tid&63)==0) sm[tid>>6] = v;
  __syncthreads();
  float s = 0.f;
  int nw = blockDim.x>>6;
  for(int i=0;i<nw;i++) s += sm[i];
  __syncthreads();
  return s;
}

__device__ __forceinline__ float softplusf(float x){
  return (x > 20.f) ? x : __logf(1.f + __expf(x));
}
__device__ __forceinline__ float siluf(float x){
  return x / (1.f + __expf(-x));
}

// one-shot prep: bf16 converts (incl xproj) + proj transpose + zero stat accumulators
__global__ void prep_weights(const float* __restrict__ in_w, const float* __restrict__ out_w,
                             const float* __restrict__ pw_w, const float* __restrict__ dpw_w,
                             const float* __restrict__ proj_w, const float* __restrict__ xproj_w,
                             bf16* __restrict__ Winb, bf16* __restrict__ Woutb,
                             bf16* __restrict__ Wub, bf16* __restrict__ Wdb,
                             bf16* __restrict__ Wxpb, float* __restrict__ PT,
                             float* __restrict__ gacc){
  int idx = blockIdx.x*256 + threadIdx.x;      // < 1,097,728
  if(idx < 6656) gacc[idx] = 0.f;              // gsum1/gssq1 + t1s/t1q/t1x
  if(idx < 524288){ Winb[idx] = f2bf(in_w[idx]); return; }
  if(idx < 786432){ int i=idx-524288; Woutb[i] = f2bf(out_w[i]); return; }
  if(idx < 851968){ int i=idx-786432; Wub[i] = f2bf(pw_w[i]); return; }
  if(idx < 917504){ int i=idx-851968; Wdb[i] = f2bf(dpw_w[i]); return; }
  if(idx < 1048576){
    int k = idx - 917504;                      // < 131072
    int i = k >> 9, j = k & 511;
    PT[j*256 + i] = proj_w[k];
    return;
  }
  int i = idx - 1048576;                       // < 49152
  Wxpb[i] = f2bf(xproj_w[i]);
}

// R1 (256 threads): load x slice coalesced; wave0 = col reduce, wave1 = row reduce
// + per-(b,c) sum/ssq of x for the fused GN3 composition
__global__ __launch_bounds__(256)
void r1_reduce_pe(const float* __restrict__ x, const float* __restrict__ pe,
                  float* __restrict__ pmax, float* __restrict__ pmin,
                  float* __restrict__ xs, float* __restrict__ xq){
  __shared__ float tile[64*65];
  __shared__ float rs_[4], rq_[4];
  int bc = blockIdx.x;          // b*256 + c
  int b = bc >> 8, c = bc & 255;
  const float* xp = x + ((size_t)bc << 12);
  float s = 0.f, q = 0.f;
  for(int i=threadIdx.x; i<4096; i+=256){
    float v = xp[i];
    tile[(i>>6)*65 + (i&63)] = v;
    s += v; q += v*v;
  }
  #pragma unroll
  for(int o=32;o>0;o>>=1){ s += __shfl_down(s, o, 64); q += __shfl_down(q, o, 64); }
  int wv = threadIdx.x >> 6, t = threadIdx.x & 63;
  if(t == 0){ rs_[wv] = s; rq_[wv] = q; }
  __syncthreads();
  if(threadIdx.x == 0){
    xs[bc] = rs_[0]+rs_[1]+rs_[2]+rs_[3];
    xq[bc] = rq_[0]+rq_[1]+rq_[2]+rq_[3];
  }
  if(wv >= 2) return;
  float coords = fmaxf((t + 0.5f)*0.25f - 0.5f, 0.f);
  int i0 = (int)floorf(coords);
  int i1 = min(i0+1, 15);
  float wg = coords - (float)i0;
  float pos = pe[c*16+i0]*(1.f-wg) + pe[c*16+i1]*wg;
  if(wv == 0){
    float cmx=-3.4e38f, cmn=3.4e38f; int cax=0, can=0;
    for(int h=0;h<64;h++){
      float v = tile[h*65 + t];
      if(v > cmx){ cmx=v; cax=h; }
      if(v < cmn){ cmn=v; can=h; }
    }
    size_t base_col = ((size_t)b*128 + t)*256 + c;
    pmax[base_col] = cmx + pos + (float)cax;
    pmin[base_col] = cmn + pos + (float)can;
  } else {
    float rmx=-3.4e38f, rmn=3.4e38f; int rax=0, ran=0;
    for(int w=0;w<64;w++){
      float v = tile[t*65 + w];
      if(v > rmx){ rmx=v; rax=w; }
      if(v < rmn){ rmn=v; ran=w; }
    }
    size_t base_row = ((size_t)b*128 + 64 + t)*256 + c;
    pmax[base_row] = rmx + pos + (float)rax;
    pmin[base_row] = rmn + pos + (float)ran;
  }
}

// paired LN over 256: rows<1024 -> A, else B; writes f32 back + bf16 copy
__global__ void ln_rows2(float* __restrict__ bufA, float* __restrict__ bufB,
                         const float* __restrict__ g, const float* __restrict__ bb,
                         bf16* __restrict__ boutA, bf16* __restrict__ boutB){
  __shared__ float sm[8];
  int row = blockIdx.x, t = threadIdx.x;
  float* buf; bf16* bout;
  if(row < 1024){ buf = bufA; bout = boutA; }
  else { buf = bufB; bout = boutB; row -= 1024; }
  float v = buf[(size_t)row*256 + t];
  float m = blk_sum(v, sm) * (1.f/256.f);
  float dv = v - m;
  float var = blk_sum(dv*dv, sm) * (1.f/256.f);
  float r = dv * rsqrtf(var + EPSV) * g[t] + bb[t];
  buf[(size_t)row*256 + t] = r;
  if(bout) bout[(size_t)row*256 + t] = f2bf(r);
}

// M1 (MFMA): xz[rb][l][i] = sum_c u_bf(b,l_eff,c) * in_w_bf[d][i][c]
__global__ __launch_bounds__(256,2)
void m1_mfma(const bf16* __restrict__ ubmax, const bf16* __restrict__ ubmin,
             const bf16* __restrict__ Win, float* __restrict__ xz){
  __shared__ bf16 att[64*264];
  int bx = blockIdx.x;
  int it = bx & 3, lt = (bx>>2)&1, b = (bx>>3)&7, r = bx>>6;
  int d = r & 1;
  const bf16* u = (r < 2) ? ubmax : ubmin;
  int flip = r & 1;
  int t = threadIdx.x;
  {
    int pr = t>>5, cc = (t&31)*8;
    #pragma unroll
    for(int i=0;i<8;i++){
      int p = pr + i*8;
      int l = lt*64 + p;
      int le = flip ? (127 - l) : l;
      short8_t v = *(const short8_t*)((const short*)u + ((size_t)(b*128 + le))*256 + cc);
      *(short8_t*)&att[p*264 + cc] = v;
    }
  }
  __syncthreads();
  int wv = t>>6, lane = t&63, quad = lane>>4, l16 = lane&15;
  int m0 = wv*64;
  f32x4_t acc[4][4];
  #pragma unroll
  for(int ms=0;ms<4;ms++)
    #pragma unroll
    for(int ns=0;ns<4;ns++) acc[ms][ns] = (f32x4_t){0.f,0.f,0.f,0.f};
  const short* wbase = (const short*)Win + ((size_t)d*1024 + it*256)*256;
  for(int k0=0;k0<256;k0+=32){
    short8_t afr[4], bfr[4];
    #pragma unroll
    for(int ms=0;ms<4;ms++)
      afr[ms] = *(const short8_t*)(wbase + (size_t)(m0 + ms*16 + l16)*256 + k0 + quad*8);
    #pragma unroll
    for(int ns=0;ns<4;ns++)
      bfr[ns] = *(const short8_t*)&att[(ns*16 + l16)*264 + k0 + quad*8];
    #pragma unroll
    for(int ms=0;ms<4;ms++)
      #pragma unroll
      for(int ns=0;ns<4;ns++)
        acc[ms][ns] = __builtin_amdgcn_mfma_f32_16x16x32_bf16(afr[ms], bfr[ns], acc[ms][ns], 0,0,0);
  }
  int rb = r*8 + b;
  #pragma unroll
  for(int ns=0;ns<4;ns++){
    int l = lt*64 + ns*16 + l16;
    float* dst = xz + ((size_t)rb*128 + l)*1024 + it*256;
    #pragma unroll
    for(int ms=0;ms<4;ms++){
      int i = m0 + ms*16 + quad*4;
      *(f32x4_t*)(dst + i) = acc[ms][ns];
    }
  }
}

// M2: conv (D_CONV=4 causal) + silu, streaming f32x4; writes xc (f32) + xcb (bf16)
__global__ __launch_bounds__(256)
void m2_conv(const float* __restrict__ xz, const float* __restrict__ cw,
             const float* __restrict__ cb, float* __restrict__ xc,
             bf16* __restrict__ xcb){
  int i4 = blockIdx.x*256 + threadIdx.x;   // < 524288
  int idx = i4 << 2;                        // element in [4096][512]
  int row = idx >> 9, dd = idx & 511;
  int gl = row & 127;
  int d = (row >> 10) & 1;
  const float* src = xz + (size_t)row*1024 + dd;
  const float* cwp = cw + (size_t)(d*512 + dd)*4;
  f32x4_t w0 = *(const f32x4_t*)(cwp);      // weights for dd+0 (k=0..3)
  f32x4_t w1 = *(const f32x4_t*)(cwp+4);
  f32x4_t w2 = *(const f32x4_t*)(cwp+8);
  f32x4_t w3 = *(const f32x4_t*)(cwp+12);
  f32x4_t bias = *(const f32x4_t*)(cb + d*512 + dd);
  f32x4_t z4 = (f32x4_t){0.f,0.f,0.f,0.f};
  f32x4_t t3 = *(const f32x4_t*)(src);
  f32x4_t t2 = (gl>=1) ? *(const f32x4_t*)(src-1024) : z4;
  f32x4_t t1 = (gl>=2) ? *(const f32x4_t*)(src-2048) : z4;
  f32x4_t t0 = (gl>=3) ? *(const f32x4_t*)(src-3072) : z4;
  f32x4_t o;
  o[0] = bias[0] + t0[0]*w0[0] + t1[0]*w0[1] + t2[0]*w0[2] + t3[0]*w0[3];
  o[1] = bias[1] + t0[1]*w1[0] + t1[1]*w1[1] + t2[1]*w1[2] + t3[1]*w1[3];
  o[2] = bias[2] + t0[2]*w2[0] + t1[2]*w2[1] + t2[2]*w2[2] + t3[2]*w2[3];
  o[3] = bias[3] + t0[3]*w3[0] + t1[3]*w3[1] + t2[3]*w3[2] + t3[3]*w3[3];
  alignas(8) bf16 ob[4];
  #pragma unroll
  for(int r=0;r<4;r++){ o[r] = siluf(o[r]); ob[r] = f2bf(o[r]); }
  *(f32x4_t*)(xc + idx) = o;
  *(short4_t*)((short*)xcb + idx) = *(const short4_t*)ob;
}

// M3 (MFMA): dbl[4096][48] = xcb[4096][512] x Wxpb[48][512]^T. 64 blocks x 4 waves.
__global__ __launch_bounds__(256)
void m3_xproj(const bf16* __restrict__ xcb, const bf16* __restrict__ Wxpb,
              float* __restrict__ dbl){
  int r0 = blockIdx.x * 64;
  int d = (r0 >> 10) & 1;
  int t = threadIdx.x;
  int wv = t>>6, lane = t&63, quad = lane>>4, l16 = lane&15;
  int rowl = wv*16 + l16;
  const short* bbase = (const short*)xcb + (size_t)(r0 + rowl)*512;
  const short* abase = (const short*)Wxpb + (size_t)d*48*512;
  f32x4_t acc[3];
  #pragma unroll
  for(int ms=0;ms<3;ms++) acc[ms] = (f32x4_t){0.f,0.f,0.f,0.f};
  #pragma unroll 4
  for(int k0=0;k0<512;k0+=32){
    short8_t bfr = *(const short8_t*)(bbase + k0 + quad*8);
    short8_t afr[3];
    #pragma unroll
    for(int ms=0;ms<3;ms++)
      afr[ms] = *(const short8_t*)(abase + (size_t)(ms*16 + l16)*512 + k0 + quad*8);
    #pragma unroll
    for(int ms=0;ms<3;ms++)
      acc[ms] = __builtin_amdgcn_mfma_f32_16x16x32_bf16(afr[ms], bfr, acc[ms], 0,0,0);
  }
  float* dst = dbl + (size_t)(r0 + rowl)*48;
  #pragma unroll
  for(int ms=0;ms<3;ms++)
    *(f32x4_t*)(dst + ms*16 + quad*4) = acc[ms];
}

// M4: dt = softplus(dbl[:, :16] . dtw^T + bias), streaming f32x4
__global__ __launch_bounds__(256)
void m4_dt(const float* __restrict__ dbl, const float* __restrict__ dtw,
           const float* __restrict__ dtbias, float* __restrict__ dt){
  int i4 = blockIdx.x*256 + threadIdx.x;   // < 524288
  int idx = i4 << 2;
  int row = idx >> 9, dd = idx & 511;
  int d = (row >> 10) & 1;
  const float* dr = dbl + (size_t)row*48;
  f32x4_t dr0 = *(const f32x4_t*)(dr);
  f32x4_t dr1 = *(const f32x4_t*)(dr+4);
  f32x4_t dr2 = *(const f32x4_t*)(dr+8);
  f32x4_t dr3 = *(const f32x4_t*)(dr+12);
  f32x4_t bias = *(const f32x4_t*)(dtbias + d*512 + dd);
  f32x4_t o;
  #pragma unroll
  for(int j=0;j<4;j++){
    const float* wp = dtw + (size_t)(d*512 + dd + j)*16;
    f32x4_t w0 = *(const f32x4_t*)(wp);
    f32x4_t w1 = *(const f32x4_t*)(wp+4);
    f32x4_t w2 = *(const f32x4_t*)(wp+8);
    f32x4_t w3 = *(const f32x4_t*)(wp+12);
    float s = bias[j];
    s += dr0[0]*w0[0] + dr0[1]*w0[1] + dr0[2]*w0[2] + dr0[3]*w0[3];
    s += dr1[0]*w1[0] + dr1[1]*w1[1] + dr1[2]*w1[2] + dr1[3]*w1[3];
    s += dr2[0]*w2[0] + dr2[1]*w2[1] + dr2[2]*w2[2] + dr2[3]*w2[3];
    s += dr3[0]*w3[0] + dr3[1]*w3[1] + dr3[2]*w3[2] + dr3[3]*w3[3];
    o[j] = softplusf(s);
  }
  *(f32x4_t*)(dt + idx) = o;
}

// M5a: chunked scan pass A
__global__ void m5_passA(const float* __restrict__ dt, const float* __restrict__ xc,
                         const float* __restrict__ dbl, const float* __restrict__ Alog,
                         float* __restrict__ P, float* __restrict__ Hl){
  int bx = blockIdx.x;
  int seg = bx & 7, half = (bx>>3)&1, rb = bx>>4;
  int dd = half*256 + threadIdx.x;
  int d = (rb>>3)&1;
  float A[16], h[16], pr[16];
  #pragma unroll
  for(int s=0;s<16;s++){
    A[s] = -__expf(Alog[(size_t)(d*512 + dd)*16 + s]);
    h[s] = 0.f; pr[s] = 1.f;
  }
  int l0 = seg*16;
  for(int l=l0;l<l0+16;l++){
    size_t row = (size_t)rb*128 + l;
    float dtv = dt[row*512 + dd];
    float xcv = xc[row*512 + dd];
    float bx_ = dtv*xcv;
    const float* dr = dbl + row*48;
    #pragma unroll
    for(int s=0;s<16;s++){
      float dA = __expf(dtv*A[s]);
      pr[s] *= dA;
      h[s] = dA*h[s] + bx_*dr[16+s];
    }
  }
  size_t o = ((size_t)(rb*8 + seg)*512 + dd)*16;
  #pragma unroll
  for(int s=0;s<16;s+=4){
    *(f32x4_t*)(P  + o + s) = (f32x4_t){pr[s],pr[s+1],pr[s+2],pr[s+3]};
    *(f32x4_t*)(Hl + o + s) = (f32x4_t){h[s],h[s+1],h[s+2],h[s+3]};
  }
}

// M5b: combine prefix, re-scan, emit y
__global__ void m5_passB(const float* __restrict__ dt, const float* __restrict__ xc,
                         const float* __restrict__ dbl, const float* __restrict__ xz,
                         const float* __restrict__ Alog, const float* __restrict__ Dp,
                         const float* __restrict__ P, const float* __restrict__ Hl,
                         bf16* __restrict__ ybb){
  int bx = blockIdx.x;
  int seg = bx & 7, half = (bx>>3)&1, rb = bx>>4;
  int dd = half*256 + threadIdx.x;
  int d = (rb>>3)&1;
  float A[16], h[16];
  #pragma unroll
  for(int s=0;s<16;s++){
    A[s] = -__expf(Alog[(size_t)(d*512 + dd)*16 + s]);
    h[s] = 0.f;
  }
  for(int j=0;j<seg;j++){
    size_t o = ((size_t)(rb*8 + j)*512 + dd)*16;
    #pragma unroll
    for(int s=0;s<16;s+=4){
      f32x4_t pv = *(const f32x4_t*)(P + o + s);
      f32x4_t hv = *(const f32x4_t*)(Hl + o + s);
      h[s]   = pv[0]*h[s]   + hv[0];
      h[s+1] = pv[1]*h[s+1] + hv[1];
      h[s+2] = pv[2]*h[s+2] + hv[2];
      h[s+3] = pv[3]*h[s+3] + hv[3];
    }
  }
  float Dv = Dp[d*512 + dd];
  int l0 = seg*16;
  for(int l=l0;l<l0+16;l++){
    size_t row = (size_t)rb*128 + l;
    float dtv = dt[row*512 + dd];
    float xcv = xc[row*512 + dd];
    float zgv = xz[row*1024 + 512 + dd];
    const float* dr = dbl + row*48;
    float bx_ = dtv*xcv;
    float y = 0.f;
    #pragma unroll
    for(int s=0;s<16;s++){
      h[s] = __expf(dtv*A[s])*h[s] + bx_*dr[16+s];
      y += h[s]*dr[32+s];
    }
    ybb[row*512 + dd] = f2bf((y + xcv*Dv) * siluf(zgv));
  }
}

// M6 (MFMA) + fused row-LN
__global__ __launch_bounds__(256,2)
void m6_mfma(const bf16* __restrict__ ybb, const bf16* __restrict__ Wout,
             const float* __restrict__ lng, const float* __restrict__ lnb,
             float* __restrict__ mo){
  __shared__ char smem[64*264*4];
  bf16* ybt = (bf16*)smem;
  float* fbuf = (float*)smem;
  int bx = blockIdx.x;
  int lt = bx & 1, b = (bx>>1)&7, r = bx>>4;
  int d = r & 1, rb = r*8 + b;
  size_t rowbase = (size_t)rb*128 + lt*64;
  int t = threadIdx.x;
  for(int i=t;i<4096;i+=256){
    int row = i>>6, c8 = (i&63)*8;
    short8_t v = *(const short8_t*)((const short*)ybb + (rowbase + row)*512 + c8);
    *(short8_t*)&ybt[row*520 + c8] = v;
  }
  __syncthreads();
  int wv = t>>6, lane = t&63, quad = lane>>4, l16 = lane&15;
  int m0 = wv*64;
  f32x4_t acc[4][4];
  #pragma unroll
  for(int ms=0;ms<4;ms++)
    #pragma unroll
    for(int ns=0;ns<4;ns++) acc[ms][ns] = (f32x4_t){0.f,0.f,0.f,0.f};
  const short* wbase = (const short*)Wout + (size_t)d*256*512;
  for(int k0=0;k0<512;k0+=32){
    short8_t afr[4], bfr[4];
    #pragma unroll
    for(int ms=0;ms<4;ms++)
      afr[ms] = *(const short8_t*)(wbase + (size_t)(m0 + ms*16 + l16)*512 + k0 + quad*8);
    #pragma unroll
    for(int ns=0;ns<4;ns++)
      bfr[ns] = *(const short8_t*)&ybt[(ns*16 + l16)*520 + k0 + quad*8];
    #pragma unroll
    for(int ms=0;ms<4;ms++)
      #pragma unroll
      for(int ns=0;ns<4;ns++)
        acc[ms][ns] = __builtin_amdgcn_mfma_f32_16x16x32_bf16(afr[ms], bfr[ns], acc[ms][ns], 0,0,0);
  }
  __syncthreads();
  #pragma unroll
  for(int ns=0;ns<4;ns++){
    int row = ns*16 + l16;
    #pragma unroll
    for(int ms=0;ms<4;ms++){
      int o = m0 + ms*16 + quad*4;
      *(f32x4_t*)(fbuf + row*264 + o) = acc[ms][ns];
    }
  }
  __syncthreads();
  {
    int row = t >> 2, part = t & 3;
    const float* fr = fbuf + row*264;
    float s = 0.f;
    #pragma unroll 8
    for(int j=0;j<64;j++){
      int col = part*64 + ((j + part*16) & 63);
      s += fr[col];
    }
    s += __shfl_xor(s, 1, 64);
    s += __shfl_xor(s, 2, 64);
    float m = s * (1.f/256.f);
    float q = 0.f;
    #pragma unroll 8
    for(int j=0;j<64;j++){
      int col = part*64 + ((j + part*16) & 63);
      float dv = fr[col] - m;
      q += dv*dv;
    }
    q += __shfl_xor(q, 1, 64);
    q += __shfl_xor(q, 2, 64);
    float rs = rsqrtf(q*(1.f/256.f) + EPSV);
    float* dst = mo + (rowbase + row)*256;
    for(int j=0;j<64;j++){
      int col = part*64 + j;
      dst[col] = (fr[col] - m)*rs*lng[col] + lnb[col];
    }
  }
}

// M7 + fused row-LN on outputs
__global__ void m7_proj(const float* __restrict__ mo, const float* __restrict__ PT,
                        const float* __restrict__ pb, const float* __restrict__ lng,
                        const float* __restrict__ lnb, float* __restrict__ resm,
                        float* __restrict__ resn){
  __shared__ float ct[16*512];
  __shared__ float fbuf[16*264];
  int bx = blockIdx.x;
  int tt = bx >> 6, rem = bx & 63, b = rem >> 3, lt = rem & 7;
  int fr_ = tt*2, br = tt*2 + 1;
  for(int i=threadIdx.x;i<16*512;i+=256){
    int lr = i >> 9, k = i & 511;
    int l = lt*16 + lr;
    ct[i] = (k < 256)
      ? mo[(((size_t)(fr_*8+b)*128) + l)*256 + k]
      : mo[(((size_t)(br*8+b)*128) + (127-l))*256 + (k-256)];
  }
  __syncthreads();
  float acc[16];
  #pragma unroll
  for(int q=0;q<16;q++) acc[q] = 0.f;
  int t = threadIdx.x;
  for(int k=0;k<512;k++){
    float pv = PT[(size_t)k*256 + t];
    #pragma unroll
    for(int q=0;q<16;q++) acc[q] += pv * ct[(q<<9) + k];
  }
  float bias = pb[t];
  #pragma unroll
  for(int q=0;q<16;q++) fbuf[q*264 + t] = acc[q] + bias;
  __syncthreads();
  float* dstbuf = tt ? resn : resm;
  if(t < 64){
    int row = t >> 2, part = t & 3;
    const float* fr = fbuf + row*264;
    float s = 0.f;
    for(int j=0;j<64;j++){
      int col = part*64 + ((j + part*16) & 63);
      s += fr[col];
    }
    s += __shfl_xor(s, 1, 64);
    s += __shfl_xor(s, 2, 64);
    float m = s * (1.f/256.f);
    float q = 0.f;
    for(int j=0;j<64;j++){
      int col = part*64 + ((j + part*16) & 63);
      float dv = fr[col] - m;
      q += dv*dv;
    }
    q += __shfl_xor(q, 1, 64);
    q += __shfl_xor(q, 2, 64);
    float rs = rsqrtf(q*(1.f/256.f) + EPSV);
    float* dst = dstbuf + ((size_t)b*128 + lt*16 + row)*256;
    for(int j=0;j<64;j++){
      int col = part*64 + j;
      dst[col] = (fr[col] - m)*rs*lng[col] + lnb[col];
    }
  }
}

// K1: stride-2 transposed depthwise 3x3 + BN + ReLU -> zT (pixel-major bf16)
__global__ __launch_bounds__(256)
void k1_deconv_T(const float* __restrict__ x, const float* __restrict__ wdw,
                 const float* __restrict__ g1, const float* __restrict__ b1,
                 bf16* __restrict__ zT){
  __shared__ float in[2*64*33];
  __shared__ bf16 ot[64*80];
  int bx = blockIdx.x;
  int cb = bx & 3, half = (bx>>2)&1, h = (bx>>3)&127, b = bx>>10;
  int c0 = cb*64, w0 = half*64, iw0 = w0>>1;
  int h_odd = h & 1;
  int ihA = h_odd ? (h-1)>>1 : h>>1;
  int ihB = (h+1)>>1;
  bool hasB = h_odd && (ihB < 64);
  for(int i = threadIdx.x; i < 4224; i += 256){
    int row = i / 2112;
    int rem = i - row*2112;
    int c = rem / 33;
    int iw = rem - c*33;
    int ihl = row ? ihB : ihA;
    bool valid = (iw0 + iw < 64) && (row == 0 || hasB);
    in[i] = valid ? x[(((size_t)b*256 + c0 + c)<<12) + (ihl<<6) + iw0 + iw] : 0.f;
  }
  __syncthreads();
  int c = threadIdx.x & 63, g = threadIdx.x >> 6;
  const float* wp = wdw + (c0+c)*9;
  int khA3 = h_odd ? 6 : 3;
  float wA0 = wp[khA3], wA1 = wp[khA3+1], wA2 = wp[khA3+2];
  float wB0 = wp[0],    wB1 = wp[1],      wB2 = wp[2];
  float scale = g1[c0+c]*BNSC, bias = b1[c0+c];
  const float* inA = in + c*33;
  const float* inB = in + 2112 + c*33;
  #pragma unroll
  for(int i=0;i<16;i++){
    int wi = g*16 + i;
    float s;
    if(!(i&1)){
      int iw = wi>>1;
      s = inA[iw]*wA1 + inB[iw]*wB1;
    } else {
      int iwa = (wi-1)>>1, iwb = (wi+1)>>1;
      s = inA[iwa]*wA2 + inA[iwb]*wA0 + inB[iwa]*wB2 + inB[iwb]*wB0;
    }
    ot[wi*80 + c] = f2bf(fmaxf(s*scale + bias, 0.f));
  }
  __syncthreads();
  int rr = threadIdx.x >> 3;
  int co = (threadIdx.x & 7) * 8;
  size_t obase = (((size_t)b*16384) + (size_t)h*128 + w0)*256 + c0;
  #pragma unroll
  for(int pass=0; pass<2; pass++){
    int wi = rr + pass*32;
    short8_t v = *(const short8_t*)&ot[wi*80 + co];
    *(short8_t*)((short*)zT + obase + (size_t)wi*256 + co) = v;
  }
}

// K2 v5 (MFMA): 64-px LDS-STAGED tile (v2's proven 1.7TB/s structure) +
// subsampled resS output + fused GN1 stats. LDS ~35KB -> 4 blocks/CU.
// grid (256, 8).
__global__ __launch_bounds__(256,4)
void k2_mfma(const bf16* __restrict__ zT, const bf16* __restrict__ Wub,
             const float* __restrict__ g2, const float* __restrict__ b2,
             const float* __restrict__ resm, const float* __restrict__ resn,
             bf16* __restrict__ resS, float* __restrict__ gsum1, float* __restrict__ gssq1){
  __shared__ bf16 zt[64*264];      // 33.8KB; reused as output staging after MFMA
  __shared__ float rm_s[256];
  __shared__ float gn_s[32], gn_q[32];
  int b = blockIdx.y;
  int p0 = blockIdx.x*64;          // 64-pixel tile (half of row h)
  int h = p0 >> 7;
  int w0 = p0 & 127;               // 0 or 64
  int t = threadIdx.x;
  if(t < 32){ gn_s[t] = 0.f; gn_q[t] = 0.f; }
  if(t >= 64 && t < 128){
    int tt = t - 64;
    *(f32x4_t*)&rm_s[tt*4] = *(const f32x4_t*)(resm + ((size_t)b*128 + h)*256 + tt*4);
  }
  // stage 64px x 256ch (32KB) into LDS, fully coalesced
  {
    const short* src = (const short*)zT + (((size_t)b*16384 + p0)*256);
    int pr = t>>5;
    int cc = (t&31)*8;
    #pragma unroll
    for(int i=0;i<8;i++){
      int p = pr + i*8;
      short8_t v = *(const short8_t*)(src + (size_t)p*256 + cc);
      *(short8_t*)&zt[p*264 + cc] = v;
    }
  }
  __syncthreads();
  int wv = t>>6, lane = t&63, quad = lane>>4, l16 = lane&15;
  int m0 = wv*64;
  f32x4_t acc[4][4];
  #pragma unroll
  for(int ms=0;ms<4;ms++)
    #pragma unroll
    for(int ns=0;ns<4;ns++) acc[ms][ns] = (f32x4_t){0.f,0.f,0.f,0.f};
  const short* wp = (const short*)Wub + (size_t)(m0 + l16)*256 + quad*8;
  short8_t afr[4];
  #pragma unroll
  for(int ms=0;ms<4;ms++) afr[ms] = *(const short8_t*)(wp + (size_t)ms*16*256);
  for(int k0=0;k0<256;k0+=32){
    short8_t anext[4];
    if(k0 + 32 < 256){
      #pragma unroll
      for(int ms=0;ms<4;ms++)
        anext[ms] = *(const short8_t*)(wp + (size_t)ms*16*256 + k0 + 32);
    }
    short8_t bfr[4];
    #pragma unroll
    for(int ns=0;ns<4;ns++)
      bfr[ns] = *(const short8_t*)&zt[(ns*16 + l16)*264 + k0 + quad*8];
    #pragma unroll
    for(int ms=0;ms<4;ms++)
      #pragma unroll
      for(int ns=0;ns<4;ns++)
        acc[ms][ns] = __builtin_amdgcn_mfma_f32_16x16x32_bf16(afr[ms], bfr[ns], acc[ms][ns], 0,0,0);
    #pragma unroll
    for(int ms=0;ms<4;ms++) afr[ms] = anext[ms];
  }
  __syncthreads();       // all waves done reading zt; reuse as output staging
  bool h_even = ((h & 1) == 0);
  float sg[4], qg[4];
  #pragma unroll
  for(int ms=0;ms<4;ms++){ sg[ms]=0.f; qg[ms]=0.f; }
  #pragma unroll
  for(int ns=0;ns<4;ns++){
    int pl = ns*16 + l16;            // local pixel 0..63 ; global w = w0 + pl
    int w = w0 + pl;
    const float* rn = resn + ((size_t)b*128 + w)*256;
    bool store = h_even && ((pl & 1) == 0);
    #pragma unroll
    for(int ms=0;ms<4;ms++){
      int o = m0 + ms*16 + quad*4;
      f32x4_t a = acc[ms][ns];
      f32x4_t gv = *(const f32x4_t*)(g2+o);
      f32x4_t bv = *(const f32x4_t*)(b2+o);
      f32x4_t rmv = *(const f32x4_t*)&rm_s[o];
      f32x4_t rnv = *(const f32x4_t*)(rn+o);
      alignas(8) bf16 ov[4];
      #pragma unroll
      for(int r=0;r<4;r++){
        float zv = a[r]*(gv[r]*BNSC) + bv[r];
        zv = fminf(fmaxf(zv, 0.f), 6.f);
        float gate = fminf(fmaxf(rmv[r]+rnv[r]+3.f, 0.f), 6.f)*(1.f/6.f);
        float vo = zv*gate;
        ov[r] = f2bf(vo);
        sg[ms] += vo;
        qg[ms] += vo*vo;
      }
      if(store) *(short4_t*)&zt[(pl>>1)*264 + o] = *(const short4_t*)ov;
    }
  }
  // GN1 partial sums: reduce over l16 lanes (pixel axis), then LDS per-group accum
  #pragma unroll
  for(int ms=0;ms<4;ms++){
    float S = sg[ms], Q = qg[ms];
    S += __shfl_xor(S, 1, 64);  Q += __shfl_xor(Q, 1, 64);
    S += __shfl_xor(S, 2, 64);  Q += __shfl_xor(Q, 2, 64);
    S += __shfl_xor(S, 4, 64);  Q += __shfl_xor(Q, 4, 64);
    S += __shfl_xor(S, 8, 64);  Q += __shfl_xor(Q, 8, 64);
    if(l16 == 0){
      int o = m0 + ms*16 + quad*4;   // 4 consecutive channels, same group o>>3
      atomicAdd(&gn_s[o>>3], S);
      atomicAdd(&gn_q[o>>3], Q);
    }
  }
  __syncthreads();
  if(t < 32){
    atomicAdd(&gsum1[b*32 + t], gn_s[t]);
    atomicAdd(&gssq1[b*32 + t], gn_q[t]);
  }
  // stream out (even h only): 32 even-w pixels -> contiguous 16KB burst
  if(h_even){
    short* dst = (short*)resS + ((size_t)b*4096 + (h>>1)*64 + (w0>>1))*256;
    #pragma unroll
    for(int it=0; it<4; it++){
      int slot = t + it*256;          // 1024 slots (32 rows x 32)
      int row = slot >> 5;
      int co = (slot & 31)*8;
      short8_t v = *(const short8_t*)&zt[row*264 + co];
      *(short8_t*)(dst + (size_t)row*256 + co) = v;
    }
  }
}

// K4 v4 (MFMA): 64-px tile (grid 64x8 -> 512 blocks, ~4 blocks/CU), reads compact
// resS, inline GN1 finalize, per-channel (sum, ssq, cross-with-x) stats.
__global__ __launch_bounds__(256,4)
void k4_mfma(const bf16* __restrict__ resS, const bf16* __restrict__ Wdb,
             const float* __restrict__ gsum1, const float* __restrict__ gssq1,
             const float* __restrict__ gng, const float* __restrict__ gnb,
             const float* __restrict__ dbg, const float* __restrict__ dbb,
             const float* __restrict__ x, float* __restrict__ t1,
             float* __restrict__ t1s, float* __restrict__ t1q, float* __restrict__ t1x){
  __shared__ bf16 at[64*264];
  __shared__ float sc[256], sb[256];
  __shared__ float stm[32], str[32];
  int b = blockIdx.y;
  int q0 = blockIdx.x*64;
  int t = threadIdx.x;
  if(t < 32){
    float m = gsum1[b*32+t] * (1.f/131072.f);
    float var = gssq1[b*32+t] * (1.f/131072.f) - m*m;
    stm[t] = m;
    str[t] = rsqrtf(var + EPSV);
  }
  __syncthreads();
  {
    int cch = t, g = cch>>3;
    float m = stm[g], rs = str[g];
    float s = rs*gng[cch];
    sc[cch] = s; sb[cch] = gnb[cch] - m*s;
  }
  __syncthreads();
  {
    int pr = t>>5;
    int cc = (t&31)*8;
    const short* src = (const short*)resS + ((size_t)b*4096 + q0)*256;
    #pragma unroll
    for(int i=0;i<8;i++){
      int q = pr + i*8;
      short8_t v = *(const short8_t*)(src + (size_t)q*256 + cc);
      const bf16* vv = (const bf16*)&v;
      alignas(16) bf16 ov[8];
      #pragma unroll
      for(int j=0;j<8;j++) ov[j] = f2bf(bf2f(vv[j])*sc[cc+j] + sb[cc+j]);
      *(short8_t*)&at[q*264 + cc] = *(const short8_t*)ov;
    }
  }
  __syncthreads();
  int wv = t>>6, lane = t&63, quad = lane>>4, l16 = lane&15;
  int n0 = wv*64;
  f32x4_t acc[4][4];
  #pragma unroll
  for(int ms=0;ms<4;ms++)
    #pragma unroll
    for(int ns=0;ns<4;ns++) acc[ms][ns] = (f32x4_t){0.f,0.f,0.f,0.f};
  const short* wp = (const short*)Wdb + (size_t)(n0 + l16)*256 + quad*8;
  short8_t bfr[4];
  #pragma unroll
  for(int ns=0;ns<4;ns++) bfr[ns] = *(const short8_t*)(wp + (size_t)ns*16*256);
  for(int k0=0;k0<256;k0+=32){
    short8_t bnext[4];
    if(k0 + 32 < 256){
      #pragma unroll
      for(int ns=0;ns<4;ns++)
        bnext[ns] = *(const short8_t*)(wp + (size_t)ns*16*256 + k0 + 32);
    }
    short8_t afr[4];
    #pragma unroll
    for(int ms=0;ms<4;ms++)
      afr[ms] = *(const short8_t*)&at[(ms*16 + l16)*264 + k0 + quad*8];
    #pragma unroll
    for(int ms=0;ms<4;ms++)
      #pragma unroll
      for(int ns=0;ns<4;ns++)
        acc[ms][ns] = __builtin_amdgcn_mfma_f32_16x16x32_bf16(afr[ms], bfr[ns], acc[ms][ns], 0,0,0);
    #pragma unroll
    for(int ns=0;ns<4;ns++) bfr[ns] = bnext[ns];
  }
  #pragma unroll
  for(int ns=0;ns<4;ns++){
    int o = n0 + ns*16 + l16;
    float s2 = dbg[o]*BNSC, bb2 = dbb[o];
    float* dst = t1 + (((size_t)b*256 + o) << 12);
    const float* xsrc = x + (((size_t)b*256 + o) << 12);
    float s_=0.f, q_=0.f, c_=0.f;
    #pragma unroll
    for(int ms=0;ms<4;ms++){
      int ps = q0 + ms*16 + quad*4;
      f32x4_t a = acc[ms][ns];
      f32x4_t xv = *(const f32x4_t*)(xsrc + ps);
      f32x4_t ov;
      #pragma unroll
      for(int r=0;r<4;r++){
        ov[r] = a[r]*s2 + bb2;
        s_ += ov[r];
        q_ += ov[r]*ov[r];
        c_ += ov[r]*xv[r];
      }
      *(f32x4_t*)(dst + ps) = ov;
    }
    // reduce over quads (pixel axis) only -> per-channel partials
    s_ += __shfl_xor(s_, 16, 64);
    q_ += __shfl_xor(q_, 16, 64);
    c_ += __shfl_xor(c_, 16, 64);
    s_ += __shfl_xor(s_, 32, 64);
    q_ += __shfl_xor(q_, 32, 64);
    c_ += __shfl_xor(c_, 32, 64);
    if(quad == 0){
      atomicAdd(&t1s[b*256 + o], s_);
      atomicAdd(&t1q[b*256 + o], q_);
      atomicAdd(&t1x[b*256 + o], c_);
    }
  }
}

// compose: per-(b,c) affine coefficients for out = A*t1 + B*x + C  (gn3(gn2(t1)+x))
__global__ void compose_gn(const float* __restrict__ t1s, const float* __restrict__ t1q,
                           const float* __restrict__ t1x, const float* __restrict__ xs,
                           const float* __restrict__ xq, const float* __restrict__ gng,
                           const float* __restrict__ gnb,
                           float* __restrict__ cA, float* __restrict__ cB, float* __restrict__ cC){
  int b = blockIdx.x, c = threadIdx.x;
  int i = b*256 + c;
  float ts = t1s[i], tq = t1q[i], tx = t1x[i];
  float sx = xs[i], qx = xq[i];
  // GN2 group stats (8 consecutive channels per group; lanes 8k..8k+7)
  float gs = ts, gq = tq;
  gs += __shfl_xor(gs,1,64); gq += __shfl_xor(gq,1,64);
  gs += __shfl_xor(gs,2,64); gq += __shfl_xor(gq,2,64);
  gs += __shfl_xor(gs,4,64); gq += __shfl_xor(gq,4,64);
  float m2 = gs*(1.f/32768.f);
  float v2 = gq*(1.f/32768.f) - m2*m2;
  float rs2 = rsqrtf(v2 + EPSV);
  float a  = rs2*gng[c];
  float bb = gnb[c] - m2*a;
  // u = a*t1 + bb + x ; per-channel stats of u
  float Su = a*ts + 4096.f*bb + sx;
  float Qu = a*a*tq + 4096.f*bb*bb + qx + 2.f*a*bb*ts + 2.f*a*tx + 2.f*bb*sx;
  float gSu = Su, gQu = Qu;
  gSu += __shfl_xor(gSu,1,64); gQu += __shfl_xor(gQu,1,64);
  gSu += __shfl_xor(gSu,2,64); gQu += __shfl_xor(gQu,2,64);
  gSu += __shfl_xor(gSu,4,64); gQu += __shfl_xor(gQu,4,64);
  float m3 = gSu*(1.f/32768.f);
  float v3 = gQu*(1.f/32768.f) - m3*m3;
  float rs3 = rsqrtf(v3 + EPSV);
  float s3 = rs3*gng[c];
  cA[i] = a*s3;
  cB[i] = s3;
  cC[i] = (bb - m3)*s3 + gnb[c];
}

// K8 v2 (float4): out = A*t1 + B*x + C   (replaces k6+k8)
__global__ void k8_gn_out(const float* __restrict__ t1, const float* __restrict__ x,
                          const float* __restrict__ cA, const float* __restrict__ cB,
                          const float* __restrict__ cC, float* __restrict__ out){
  int i4 = blockIdx.x*256 + threadIdx.x;
  int idx = i4 << 2;
  int c = (idx >> 12) & 255, b = idx >> 20;
  int i = b*256 + c;
  float A = cA[i], Bv = cB[i], C = cC[i];
  f32x4_t tv = *(const f32x4_t*)(t1 + idx);
  f32x4_t xv = *(const f32x4_t*)(x + idx);
  f32x4_t ov;
  #pragma unroll
  for(int r=0;r<4;r++) ov[r] = A*tv[r] + Bv*xv[r] + C;
  *(f32x4_t*)(out + idx) = ov;
}

extern "C" void kernel_launch(void* const* d_in, const int* in_sizes, int n_in,
                              void* d_out, int out_size, void* d_ws, size_t ws_size,
                              hipStream_t stream){
  const float* x      = (const float*)d_in[0];
  const float* pos    = (const float*)d_in[1];
  const float* ln_g   = (const float*)d_in[2];
  const float* ln_b   = (const float*)d_in[3];
  const float* in_w   = (const float*)d_in[4];
  const float* conv_w = (const float*)d_in[5];
  const float* conv_b = (const float*)d_in[6];
  const float* xproj  = (const float*)d_in[7];
  const float* dt_w   = (const float*)d_in[8];
  const float* dt_b   = (const float*)d_in[9];
  const float* A_log  = (const float*)d_in[10];
  const float* Dp     = (const float*)d_in[11];
  const float* out_w  = (const float*)d_in[12];
  const float* proj_w = (const float*)d_in[13];
  const float* proj_b = (const float*)d_in[14];
  const float* dw_w   = (const float*)d_in[15];
  const float* bn1g   = (const float*)d_in[16];
  const float* bn1b   = (const float*)d_in[17];
  const float* pw_w   = (const float*)d_in[18];
  const float* bn2g   = (const float*)d_in[19];
  const float* bn2b   = (const float*)d_in[20];
  const float* dpw_w  = (const float*)d_in[21];
  const float* dbng   = (const float*)d_in[22];
  const float* dbnb   = (const float*)d_in[23];
  const float* gng    = (const float*)d_in[24];
  const float* gnb    = (const float*)d_in[25];
  float* out = (float*)d_out;

  float* ws = (float*)d_ws;
  bf16*  resS = (bf16*)ws;                       // compact subsampled (b,4096,256), 16MB
  bf16*  zT   = (bf16*)(ws + 16777216);          // pixel-major (b,p,c), 64MB
  float* scanP = ws + 16777216;                  // overlay of zT region
  float* scanH = ws + 16777216 + 2097152;
  float* zone = ws + 33554432;
  float* xz   = zone;                            // 4,194,304
  float* xc   = xz  + 4194304;                   // 2,097,152
  float* dbl  = xc  + 2097152;                   //   196,608
  float* dtb  = dbl + 196608;                    // 2,097,152
  bf16*  ybb  = (bf16*)(dtb + 2097152);          // 1,048,576 f worth
  bf16*  xcb  = (bf16*)(dtb + 2097152 + 524288); // 1,048,576 f worth (2M bf16)
  float* t1   = zone;                            // overlay (first 8,388,608)
  float* mo   = zone + 9633792;                  // 1,048,576
  float* resm = mo   + 1048576;
  float* resn = resm + 262144;
  float* pmax = resn + 262144;
  float* pmin = pmax + 262144;
  float* PT   = pmin + 262144;
  bf16*  ubmax= (bf16*)(PT + 131072);
  bf16*  ubmin= (bf16*)(PT + 131072 + 131072);
  bf16*  Winb = (bf16*)(PT + 131072 + 262144);
  bf16*  Woutb= (bf16*)(PT + 131072 + 524288);
  bf16*  Wub  = (bf16*)(PT + 131072 + 655360);
  bf16*  Wdb  = (bf16*)(PT + 131072 + 688128);
  bf16*  Wxpb = (bf16*)(PT + 131072 + 720896);   // 49152 bf16 = 24576 floats
  float* gacc = PT + 131072 + 745472;
  float* gsum1 = gacc,        *gssq1 = gacc + 256;
  float* t1s = gacc + 512;
  float* t1q = gacc + 2560;
  float* t1x = gacc + 4608;
  float* xs  = gacc + 6656;
  float* xq  = gacc + 8704;
  float* cA  = gacc + 10752;
  float* cB  = gacc + 12800;
  float* cC  = gacc + 14848;

  prep_weights<<<4288,256,0,stream>>>(in_w, out_w, pw_w, dpw_w, proj_w, xproj,
                                      Winb, Woutb, Wub, Wdb, Wxpb, PT, gacc);

  r1_reduce_pe<<<2048,256,0,stream>>>(x, pos, pmax, pmin, xs, xq);
  ln_rows2<<<2048,256,0,stream>>>(pmax, pmin, ln_g, ln_b, ubmax, ubmin);

  m1_mfma<<<256,256,0,stream>>>(ubmax, ubmin, Winb, xz);
  m2_conv<<<2048,256,0,stream>>>(xz, conv_w, conv_b, xc, xcb);
  m3_xproj<<<64,256,0,stream>>>(xcb, Wxpb, dbl);
  m4_dt<<<2048,256,0,stream>>>(dbl, dt_w, dt_b, dtb);
  m5_passA<<<512,256,0,stream>>>(dtb, xc, dbl, A_log, scanP, scanH);
  m5_passB<<<512,256,0,stream>>>(dtb, xc, dbl, xz, A_log, Dp, scanP, scanH, ybb);
  m6_mfma<<<64,256,0,stream>>>(ybb, Woutb, ln_g, ln_b, mo);
  m7_proj<<<128,256,0,stream>>>(mo, PT, proj_b, ln_g, ln_b, resm, resn);

  k1_deconv_T<<<8192,256,0,stream>>>(x, dw_w, bn1g, bn1b, zT);
  k2_mfma<<<dim3(256,8),256,0,stream>>>(zT, Wub, bn2g, bn2b, resm, resn, resS,
                                        gsum1, gssq1);

  k4_mfma<<<dim3(64,8),256,0,stream>>>(resS, Wdb, gsum1, gssq1,
                                       gng, gnb, dbng, dbnb, x, t1, t1s, t1q, t1x);

  compose_gn<<<8,256,0,stream>>>(t1s, t1q, t1x, xs, xq, gng, gnb, cA, cB, cC);
  k8_gn_out<<<8192,256,0,stream>>>(t1, x, cA, cB, cC, out);
}

// Round 9
// 476.703 us; speedup vs baseline: 1.0373x; 1.0019x over previous
//
#include <hip/hip_runtime.h>
#include <hip/hip_bf16.h>
#include <math.h>

typedef __hip_bfloat16 bf16;
typedef __attribute__((ext_vector_type(8))) short short8_t;
typedef __attribute__((ext_vector_type(4))) short short4_t;
typedef __attribute__((ext_vector_type(4))) float f32x4_t;

#define EPSV 1e-5f
#define BNSC 0.99999500003749968f  // 1/sqrt(1+1e-5)

__device__ __forceinline__ float bf2f(bf16 v){ return __bfloat162float(v); }
__device__ __forceinline__ bf16 f2bf(float v){ return __float2bfloat16(v); }

__device__ __forceinline__ float blk_sum(float v, float* sm){
  int tid = threadIdx.x;
  #pragma unroll
  for(int o=32;o>0;o>>=1) v += __shfl_down(v, o, 64);
  if((tid&63)==0) sm[tid>>6] = v;
  __syncthreads();
  float s = 0.f;
  int nw = blockDim.x>>6;
  for(int i=0;i<nw;i++) s += sm[i];
  __syncthreads();
  return s;
}

__device__ __forceinline__ float softplusf(float x){
  return (x > 20.f) ? x : __logf(1.f + __expf(x));
}
__device__ __forceinline__ float siluf(float x){
  return x / (1.f + __expf(-x));
}

// one-shot prep: bf16 converts (incl xproj) + proj transpose + zero stat accumulators
__global__ void prep_weights(const float* __restrict__ in_w, const float* __restrict__ out_w,
                             const float* __restrict__ pw_w, const float* __restrict__ dpw_w,
                             const float* __restrict__ proj_w, const float* __restrict__ xproj_w,
                             bf16* __restrict__ Winb, bf16* __restrict__ Woutb,
                             bf16* __restrict__ Wub, bf16* __restrict__ Wdb,
                             bf16* __restrict__ Wxpb, float* __restrict__ PT,
                             float* __restrict__ gacc){
  int idx = blockIdx.x*256 + threadIdx.x;      // < 1,097,728
  if(idx < 6656) gacc[idx] = 0.f;              // gsum1/gssq1 + t1s/t1q/t1x
  if(idx < 524288){ Winb[idx] = f2bf(in_w[idx]); return; }
  if(idx < 786432){ int i=idx-524288; Woutb[i] = f2bf(out_w[i]); return; }
  if(idx < 851968){ int i=idx-786432; Wub[i] = f2bf(pw_w[i]); return; }
  if(idx < 917504){ int i=idx-851968; Wdb[i] = f2bf(dpw_w[i]); return; }
  if(idx < 1048576){
    int k = idx - 917504;                      // < 131072
    int i = k >> 9, j = k & 511;
    PT[j*256 + i] = proj_w[k];
    return;
  }
  int i = idx - 1048576;                       // < 49152
  Wxpb[i] = f2bf(xproj_w[i]);
}

// R1 (256 threads): load x slice coalesced; wave0 = col reduce, wave1 = row reduce
// + per-(b,c) sum/ssq of x for the fused GN3 composition
__global__ __launch_bounds__(256)
void r1_reduce_pe(const float* __restrict__ x, const float* __restrict__ pe,
                  float* __restrict__ pmax, float* __restrict__ pmin,
                  float* __restrict__ xs, float* __restrict__ xq){
  __shared__ float tile[64*65];
  __shared__ float rs_[4], rq_[4];
  int bc = blockIdx.x;          // b*256 + c
  int b = bc >> 8, c = bc & 255;
  const float* xp = x + ((size_t)bc << 12);
  float s = 0.f, q = 0.f;
  for(int i=threadIdx.x; i<4096; i+=256){
    float v = xp[i];
    tile[(i>>6)*65 + (i&63)] = v;
    s += v; q += v*v;
  }
  #pragma unroll
  for(int o=32;o>0;o>>=1){ s += __shfl_down(s, o, 64); q += __shfl_down(q, o, 64); }
  int wv = threadIdx.x >> 6, t = threadIdx.x & 63;
  if(t == 0){ rs_[wv] = s; rq_[wv] = q; }
  __syncthreads();
  if(threadIdx.x == 0){
    xs[bc] = rs_[0]+rs_[1]+rs_[2]+rs_[3];
    xq[bc] = rq_[0]+rq_[1]+rq_[2]+rq_[3];
  }
  if(wv >= 2) return;
  float coords = fmaxf((t + 0.5f)*0.25f - 0.5f, 0.f);
  int i0 = (int)floorf(coords);
  int i1 = min(i0+1, 15);
  float wg = coords - (float)i0;
  float pos = pe[c*16+i0]*(1.f-wg) + pe[c*16+i1]*wg;
  if(wv == 0){
    float cmx=-3.4e38f, cmn=3.4e38f; int cax=0, can=0;
    for(int h=0;h<64;h++){
      float v = tile[h*65 + t];
      if(v > cmx){ cmx=v; cax=h; }
      if(v < cmn){ cmn=v; can=h; }
    }
    size_t base_col = ((size_t)b*128 + t)*256 + c;
    pmax[base_col] = cmx + pos + (float)cax;
    pmin[base_col] = cmn + pos + (float)can;
  } else {
    float rmx=-3.4e38f, rmn=3.4e38f; int rax=0, ran=0;
    for(int w=0;w<64;w++){
      float v = tile[t*65 + w];
      if(v > rmx){ rmx=v; rax=w; }
      if(v < rmn){ rmn=v; ran=w; }
    }
    size_t base_row = ((size_t)b*128 + 64 + t)*256 + c;
    pmax[base_row] = rmx + pos + (float)rax;
    pmin[base_row] = rmn + pos + (float)ran;
  }
}

// paired LN over 256: rows<1024 -> A, else B; writes f32 back + bf16 copy
__global__ void ln_rows2(float* __restrict__ bufA, float* __restrict__ bufB,
                         const float* __restrict__ g, const float* __restrict__ bb,
                         bf16* __restrict__ boutA, bf16* __restrict__ boutB){
  __shared__ float sm[8];
  int row = blockIdx.x, t = threadIdx.x;
  float* buf; bf16* bout;
  if(row < 1024){ buf = bufA; bout = boutA; }
  else { buf = bufB; bout = boutB; row -= 1024; }
  float v = buf[(size_t)row*256 + t];
  float m = blk_sum(v, sm) * (1.f/256.f);
  float dv = v - m;
  float var = blk_sum(dv*dv, sm) * (1.f/256.f);
  float r = dv * rsqrtf(var + EPSV) * g[t] + bb[t];
  buf[(size_t)row*256 + t] = r;
  if(bout) bout[(size_t)row*256 + t] = f2bf(r);
}

// M1 (MFMA): xz[rb][l][i] = sum_c u_bf(b,l_eff,c) * in_w_bf[d][i][c]
__global__ __launch_bounds__(256,2)
void m1_mfma(const bf16* __restrict__ ubmax, const bf16* __restrict__ ubmin,
             const bf16* __restrict__ Win, float* __restrict__ xz){
  __shared__ bf16 att[64*264];
  int bx = blockIdx.x;
  int it = bx & 3, lt = (bx>>2)&1, b = (bx>>3)&7, r = bx>>6;
  int d = r & 1;
  const bf16* u = (r < 2) ? ubmax : ubmin;
  int flip = r & 1;
  int t = threadIdx.x;
  {
    int pr = t>>5, cc = (t&31)*8;
    #pragma unroll
    for(int i=0;i<8;i++){
      int p = pr + i*8;
      int l = lt*64 + p;
      int le = flip ? (127 - l) : l;
      short8_t v = *(const short8_t*)((const short*)u + ((size_t)(b*128 + le))*256 + cc);
      *(short8_t*)&att[p*264 + cc] = v;
    }
  }
  __syncthreads();
  int wv = t>>6, lane = t&63, quad = lane>>4, l16 = lane&15;
  int m0 = wv*64;
  f32x4_t acc[4][4];
  #pragma unroll
  for(int ms=0;ms<4;ms++)
    #pragma unroll
    for(int ns=0;ns<4;ns++) acc[ms][ns] = (f32x4_t){0.f,0.f,0.f,0.f};
  const short* wbase = (const short*)Win + ((size_t)d*1024 + it*256)*256;
  for(int k0=0;k0<256;k0+=32){
    short8_t afr[4], bfr[4];
    #pragma unroll
    for(int ms=0;ms<4;ms++)
      afr[ms] = *(const short8_t*)(wbase + (size_t)(m0 + ms*16 + l16)*256 + k0 + quad*8);
    #pragma unroll
    for(int ns=0;ns<4;ns++)
      bfr[ns] = *(const short8_t*)&att[(ns*16 + l16)*264 + k0 + quad*8];
    #pragma unroll
    for(int ms=0;ms<4;ms++)
      #pragma unroll
      for(int ns=0;ns<4;ns++)
        acc[ms][ns] = __builtin_amdgcn_mfma_f32_16x16x32_bf16(afr[ms], bfr[ns], acc[ms][ns], 0,0,0);
  }
  int rb = r*8 + b;
  #pragma unroll
  for(int ns=0;ns<4;ns++){
    int l = lt*64 + ns*16 + l16;
    float* dst = xz + ((size_t)rb*128 + l)*1024 + it*256;
    #pragma unroll
    for(int ms=0;ms<4;ms++){
      int i = m0 + ms*16 + quad*4;
      *(f32x4_t*)(dst + i) = acc[ms][ns];
    }
  }
}

// M2: conv (D_CONV=4 causal) + silu, streaming f32x4; writes xc (f32) + xcb (bf16)
__global__ __launch_bounds__(256)
void m2_conv(const float* __restrict__ xz, const float* __restrict__ cw,
             const float* __restrict__ cb, float* __restrict__ xc,
             bf16* __restrict__ xcb){
  int i4 = blockIdx.x*256 + threadIdx.x;   // < 524288
  int idx = i4 << 2;                        // element in [4096][512]
  int row = idx >> 9, dd = idx & 511;
  int gl = row & 127;
  int d = (row >> 10) & 1;
  const float* src = xz + (size_t)row*1024 + dd;
  const float* cwp = cw + (size_t)(d*512 + dd)*4;
  f32x4_t w0 = *(const f32x4_t*)(cwp);      // weights for dd+0 (k=0..3)
  f32x4_t w1 = *(const f32x4_t*)(cwp+4);
  f32x4_t w2 = *(const f32x4_t*)(cwp+8);
  f32x4_t w3 = *(const f32x4_t*)(cwp+12);
  f32x4_t bias = *(const f32x4_t*)(cb + d*512 + dd);
  f32x4_t z4 = (f32x4_t){0.f,0.f,0.f,0.f};
  f32x4_t t3 = *(const f32x4_t*)(src);
  f32x4_t t2 = (gl>=1) ? *(const f32x4_t*)(src-1024) : z4;
  f32x4_t t1 = (gl>=2) ? *(const f32x4_t*)(src-2048) : z4;
  f32x4_t t0 = (gl>=3) ? *(const f32x4_t*)(src-3072) : z4;
  f32x4_t o;
  o[0] = bias[0] + t0[0]*w0[0] + t1[0]*w0[1] + t2[0]*w0[2] + t3[0]*w0[3];
  o[1] = bias[1] + t0[1]*w1[0] + t1[1]*w1[1] + t2[1]*w1[2] + t3[1]*w1[3];
  o[2] = bias[2] + t0[2]*w2[0] + t1[2]*w2[1] + t2[2]*w2[2] + t3[2]*w2[3];
  o[3] = bias[3] + t0[3]*w3[0] + t1[3]*w3[1] + t2[3]*w3[2] + t3[3]*w3[3];
  alignas(8) bf16 ob[4];
  #pragma unroll
  for(int r=0;r<4;r++){ o[r] = siluf(o[r]); ob[r] = f2bf(o[r]); }
  *(f32x4_t*)(xc + idx) = o;
  *(short4_t*)((short*)xcb + idx) = *(const short4_t*)ob;
}

// M3 (MFMA): dbl[4096][48] = xcb[4096][512] x Wxpb[48][512]^T. 64 blocks x 4 waves.
__global__ __launch_bounds__(256)
void m3_xproj(const bf16* __restrict__ xcb, const bf16* __restrict__ Wxpb,
              float* __restrict__ dbl){
  int r0 = blockIdx.x * 64;
  int d = (r0 >> 10) & 1;
  int t = threadIdx.x;
  int wv = t>>6, lane = t&63, quad = lane>>4, l16 = lane&15;
  int rowl = wv*16 + l16;
  const short* bbase = (const short*)xcb + (size_t)(r0 + rowl)*512;
  const short* abase = (const short*)Wxpb + (size_t)d*48*512;
  f32x4_t acc[3];
  #pragma unroll
  for(int ms=0;ms<3;ms++) acc[ms] = (f32x4_t){0.f,0.f,0.f,0.f};
  #pragma unroll 4
  for(int k0=0;k0<512;k0+=32){
    short8_t bfr = *(const short8_t*)(bbase + k0 + quad*8);
    short8_t afr[3];
    #pragma unroll
    for(int ms=0;ms<3;ms++)
      afr[ms] = *(const short8_t*)(abase + (size_t)(ms*16 + l16)*512 + k0 + quad*8);
    #pragma unroll
    for(int ms=0;ms<3;ms++)
      acc[ms] = __builtin_amdgcn_mfma_f32_16x16x32_bf16(afr[ms], bfr, acc[ms], 0,0,0);
  }
  float* dst = dbl + (size_t)(r0 + rowl)*48;
  #pragma unroll
  for(int ms=0;ms<3;ms++)
    *(f32x4_t*)(dst + ms*16 + quad*4) = acc[ms];
}

// M4: dt = softplus(dbl[:, :16] . dtw^T + bias), streaming f32x4
__global__ __launch_bounds__(256)
void m4_dt(const float* __restrict__ dbl, const float* __restrict__ dtw,
           const float* __restrict__ dtbias, float* __restrict__ dt){
  int i4 = blockIdx.x*256 + threadIdx.x;   // < 524288
  int idx = i4 << 2;
  int row = idx >> 9, dd = idx & 511;
  int d = (row >> 10) & 1;
  const float* dr = dbl + (size_t)row*48;
  f32x4_t dr0 = *(const f32x4_t*)(dr);
  f32x4_t dr1 = *(const f32x4_t*)(dr+4);
  f32x4_t dr2 = *(const f32x4_t*)(dr+8);
  f32x4_t dr3 = *(const f32x4_t*)(dr+12);
  f32x4_t bias = *(const f32x4_t*)(dtbias + d*512 + dd);
  f32x4_t o;
  #pragma unroll
  for(int j=0;j<4;j++){
    const float* wp = dtw + (size_t)(d*512 + dd + j)*16;
    f32x4_t w0 = *(const f32x4_t*)(wp);
    f32x4_t w1 = *(const f32x4_t*)(wp+4);
    f32x4_t w2 = *(const f32x4_t*)(wp+8);
    f32x4_t w3 = *(const f32x4_t*)(wp+12);
    float s = bias[j];
    s += dr0[0]*w0[0] + dr0[1]*w0[1] + dr0[2]*w0[2] + dr0[3]*w0[3];
    s += dr1[0]*w1[0] + dr1[1]*w1[1] + dr1[2]*w1[2] + dr1[3]*w1[3];
    s += dr2[0]*w2[0] + dr2[1]*w2[1] + dr2[2]*w2[2] + dr2[3]*w2[3];
    s += dr3[0]*w3[0] + dr3[1]*w3[1] + dr3[2]*w3[2] + dr3[3]*w3[3];
    o[j] = softplusf(s);
  }
  *(f32x4_t*)(dt + idx) = o;
}

// M5a: chunked scan pass A
__global__ void m5_passA(const float* __restrict__ dt, const float* __restrict__ xc,
                         const float* __restrict__ dbl, const float* __restrict__ Alog,
                         float* __restrict__ P, float* __restrict__ Hl){
  int bx = blockIdx.x;
  int seg = bx & 7, half = (bx>>3)&1, rb = bx>>4;
  int dd = half*256 + threadIdx.x;
  int d = (rb>>3)&1;
  float A[16], h[16], pr[16];
  #pragma unroll
  for(int s=0;s<16;s++){
    A[s] = -__expf(Alog[(size_t)(d*512 + dd)*16 + s]);
    h[s] = 0.f; pr[s] = 1.f;
  }
  int l0 = seg*16;
  for(int l=l0;l<l0+16;l++){
    size_t row = (size_t)rb*128 + l;
    float dtv = dt[row*512 + dd];
    float xcv = xc[row*512 + dd];
    float bx_ = dtv*xcv;
    const float* dr = dbl + row*48;
    #pragma unroll
    for(int s=0;s<16;s++){
      float dA = __expf(dtv*A[s]);
      pr[s] *= dA;
      h[s] = dA*h[s] + bx_*dr[16+s];
    }
  }
  size_t o = ((size_t)(rb*8 + seg)*512 + dd)*16;
  #pragma unroll
  for(int s=0;s<16;s+=4){
    *(f32x4_t*)(P  + o + s) = (f32x4_t){pr[s],pr[s+1],pr[s+2],pr[s+3]};
    *(f32x4_t*)(Hl + o + s) = (f32x4_t){h[s],h[s+1],h[s+2],h[s+3]};
  }
}

// M5b: combine prefix, re-scan, emit y
__global__ void m5_passB(const float* __restrict__ dt, const float* __restrict__ xc,
                         const float* __restrict__ dbl, const float* __restrict__ xz,
                         const float* __restrict__ Alog, const float* __restrict__ Dp,
                         const float* __restrict__ P, const float* __restrict__ Hl,
                         bf16* __restrict__ ybb){
  int bx = blockIdx.x;
  int seg = bx & 7, half = (bx>>3)&1, rb = bx>>4;
  int dd = half*256 + threadIdx.x;
  int d = (rb>>3)&1;
  float A[16], h[16];
  #pragma unroll
  for(int s=0;s<16;s++){
    A[s] = -__expf(Alog[(size_t)(d*512 + dd)*16 + s]);
    h[s] = 0.f;
  }
  for(int j=0;j<seg;j++){
    size_t o = ((size_t)(rb*8 + j)*512 + dd)*16;
    #pragma unroll
    for(int s=0;s<16;s+=4){
      f32x4_t pv = *(const f32x4_t*)(P + o + s);
      f32x4_t hv = *(const f32x4_t*)(Hl + o + s);
      h[s]   = pv[0]*h[s]   + hv[0];
      h[s+1] = pv[1]*h[s+1] + hv[1];
      h[s+2] = pv[2]*h[s+2] + hv[2];
      h[s+3] = pv[3]*h[s+3] + hv[3];
    }
  }
  float Dv = Dp[d*512 + dd];
  int l0 = seg*16;
  for(int l=l0;l<l0+16;l++){
    size_t row = (size_t)rb*128 + l;
    float dtv = dt[row*512 + dd];
    float xcv = xc[row*512 + dd];
    float zgv = xz[row*1024 + 512 + dd];
    const float* dr = dbl + row*48;
    float bx_ = dtv*xcv;
    float y = 0.f;
    #pragma unroll
    for(int s=0;s<16;s++){
      h[s] = __expf(dtv*A[s])*h[s] + bx_*dr[16+s];
      y += h[s]*dr[32+s];
    }
    ybb[row*512 + dd] = f2bf((y + xcv*Dv) * siluf(zgv));
  }
}

// M6 (MFMA) + fused row-LN
__global__ __launch_bounds__(256,2)
void m6_mfma(const bf16* __restrict__ ybb, const bf16* __restrict__ Wout,
             const float* __restrict__ lng, const float* __restrict__ lnb,
             float* __restrict__ mo){
  __shared__ char smem[64*264*4];
  bf16* ybt = (bf16*)smem;
  float* fbuf = (float*)smem;
  int bx = blockIdx.x;
  int lt = bx & 1, b = (bx>>1)&7, r = bx>>4;
  int d = r & 1, rb = r*8 + b;
  size_t rowbase = (size_t)rb*128 + lt*64;
  int t = threadIdx.x;
  for(int i=t;i<4096;i+=256){
    int row = i>>6, c8 = (i&63)*8;
    short8_t v = *(const short8_t*)((const short*)ybb + (rowbase + row)*512 + c8);
    *(short8_t*)&ybt[row*520 + c8] = v;
  }
  __syncthreads();
  int wv = t>>6, lane = t&63, quad = lane>>4, l16 = lane&15;
  int m0 = wv*64;
  f32x4_t acc[4][4];
  #pragma unroll
  for(int ms=0;ms<4;ms++)
    #pragma unroll
    for(int ns=0;ns<4;ns++) acc[ms][ns] = (f32x4_t){0.f,0.f,0.f,0.f};
  const short* wbase = (const short*)Wout + (size_t)d*256*512;
  for(int k0=0;k0<512;k0+=32){
    short8_t afr[4], bfr[4];
    #pragma unroll
    for(int ms=0;ms<4;ms++)
      afr[ms] = *(const short8_t*)(wbase + (size_t)(m0 + ms*16 + l16)*512 + k0 + quad*8);
    #pragma unroll
    for(int ns=0;ns<4;ns++)
      bfr[ns] = *(const short8_t*)&ybt[(ns*16 + l16)*520 + k0 + quad*8];
    #pragma unroll
    for(int ms=0;ms<4;ms++)
      #pragma unroll
      for(int ns=0;ns<4;ns++)
        acc[ms][ns] = __builtin_amdgcn_mfma_f32_16x16x32_bf16(afr[ms], bfr[ns], acc[ms][ns], 0,0,0);
  }
  __syncthreads();
  #pragma unroll
  for(int ns=0;ns<4;ns++){
    int row = ns*16 + l16;
    #pragma unroll
    for(int ms=0;ms<4;ms++){
      int o = m0 + ms*16 + quad*4;
      *(f32x4_t*)(fbuf + row*264 + o) = acc[ms][ns];
    }
  }
  __syncthreads();
  {
    int row = t >> 2, part = t & 3;
    const float* fr = fbuf + row*264;
    float s = 0.f;
    #pragma unroll 8
    for(int j=0;j<64;j++){
      int col = part*64 + ((j + part*16) & 63);
      s += fr[col];
    }
    s += __shfl_xor(s, 1, 64);
    s += __shfl_xor(s, 2, 64);
    float m = s * (1.f/256.f);
    float q = 0.f;
    #pragma unroll 8
    for(int j=0;j<64;j++){
      int col = part*64 + ((j + part*16) & 63);
      float dv = fr[col] - m;
      q += dv*dv;
    }
    q += __shfl_xor(q, 1, 64);
    q += __shfl_xor(q, 2, 64);
    float rs = rsqrtf(q*(1.f/256.f) + EPSV);
    float* dst = mo + (rowbase + row)*256;
    for(int j=0;j<64;j++){
      int col = part*64 + j;
      dst[col] = (fr[col] - m)*rs*lng[col] + lnb[col];
    }
  }
}

// M7 + fused row-LN on outputs
__global__ void m7_proj(const float* __restrict__ mo, const float* __restrict__ PT,
                        const float* __restrict__ pb, const float* __restrict__ lng,
                        const float* __restrict__ lnb, float* __restrict__ resm,
                        float* __restrict__ resn){
  __shared__ float ct[16*512];
  __shared__ float fbuf[16*264];
  int bx = blockIdx.x;
  int tt = bx >> 6, rem = bx & 63, b = rem >> 3, lt = rem & 7;
  int fr_ = tt*2, br = tt*2 + 1;
  for(int i=threadIdx.x;i<16*512;i+=256){
    int lr = i >> 9, k = i & 511;
    int l = lt*16 + lr;
    ct[i] = (k < 256)
      ? mo[(((size_t)(fr_*8+b)*128) + l)*256 + k]
      : mo[(((size_t)(br*8+b)*128) + (127-l))*256 + (k-256)];
  }
  __syncthreads();
  float acc[16];
  #pragma unroll
  for(int q=0;q<16;q++) acc[q] = 0.f;
  int t = threadIdx.x;
  for(int k=0;k<512;k++){
    float pv = PT[(size_t)k*256 + t];
    #pragma unroll
    for(int q=0;q<16;q++) acc[q] += pv * ct[(q<<9) + k];
  }
  float bias = pb[t];
  #pragma unroll
  for(int q=0;q<16;q++) fbuf[q*264 + t] = acc[q] + bias;
  __syncthreads();
  float* dstbuf = tt ? resn : resm;
  if(t < 64){
    int row = t >> 2, part = t & 3;
    const float* fr = fbuf + row*264;
    float s = 0.f;
    for(int j=0;j<64;j++){
      int col = part*64 + ((j + part*16) & 63);
      s += fr[col];
    }
    s += __shfl_xor(s, 1, 64);
    s += __shfl_xor(s, 2, 64);
    float m = s * (1.f/256.f);
    float q = 0.f;
    for(int j=0;j<64;j++){
      int col = part*64 + ((j + part*16) & 63);
      float dv = fr[col] - m;
      q += dv*dv;
    }
    q += __shfl_xor(q, 1, 64);
    q += __shfl_xor(q, 2, 64);
    float rs = rsqrtf(q*(1.f/256.f) + EPSV);
    float* dst = dstbuf + ((size_t)b*128 + lt*16 + row)*256;
    for(int j=0;j<64;j++){
      int col = part*64 + j;
      dst[col] = (fr[col] - m)*rs*lng[col] + lnb[col];
    }
  }
}

// K1: stride-2 transposed depthwise 3x3 + BN + ReLU -> zT (pixel-major bf16)
__global__ __launch_bounds__(256)
void k1_deconv_T(const float* __restrict__ x, const float* __restrict__ wdw,
                 const float* __restrict__ g1, const float* __restrict__ b1,
                 bf16* __restrict__ zT){
  __shared__ float in[2*64*33];
  __shared__ bf16 ot[64*80];
  int bx = blockIdx.x;
  int cb = bx & 3, half = (bx>>2)&1, h = (bx>>3)&127, b = bx>>10;
  int c0 = cb*64, w0 = half*64, iw0 = w0>>1;
  int h_odd = h & 1;
  int ihA = h_odd ? (h-1)>>1 : h>>1;
  int ihB = (h+1)>>1;
  bool hasB = h_odd && (ihB < 64);
  for(int i = threadIdx.x; i < 4224; i += 256){
    int row = i / 2112;
    int rem = i - row*2112;
    int c = rem / 33;
    int iw = rem - c*33;
    int ihl = row ? ihB : ihA;
    bool valid = (iw0 + iw < 64) && (row == 0 || hasB);
    in[i] = valid ? x[(((size_t)b*256 + c0 + c)<<12) + (ihl<<6) + iw0 + iw] : 0.f;
  }
  __syncthreads();
  int c = threadIdx.x & 63, g = threadIdx.x >> 6;
  const float* wp = wdw + (c0+c)*9;
  int khA3 = h_odd ? 6 : 3;
  float wA0 = wp[khA3], wA1 = wp[khA3+1], wA2 = wp[khA3+2];
  float wB0 = wp[0],    wB1 = wp[1],      wB2 = wp[2];
  float scale = g1[c0+c]*BNSC, bias = b1[c0+c];
  const float* inA = in + c*33;
  const float* inB = in + 2112 + c*33;
  #pragma unroll
  for(int i=0;i<16;i++){
    int wi = g*16 + i;
    float s;
    if(!(i&1)){
      int iw = wi>>1;
      s = inA[iw]*wA1 + inB[iw]*wB1;
    } else {
      int iwa = (wi-1)>>1, iwb = (wi+1)>>1;
      s = inA[iwa]*wA2 + inA[iwb]*wA0 + inB[iwa]*wB2 + inB[iwb]*wB0;
    }
    ot[wi*80 + c] = f2bf(fmaxf(s*scale + bias, 0.f));
  }
  __syncthreads();
  int rr = threadIdx.x >> 3;
  int co = (threadIdx.x & 7) * 8;
  size_t obase = (((size_t)b*16384) + (size_t)h*128 + w0)*256 + c0;
  #pragma unroll
  for(int pass=0; pass<2; pass++){
    int wi = rr + pass*32;
    short8_t v = *(const short8_t*)&ot[wi*80 + co];
    *(short8_t*)((short*)zT + obase + (size_t)wi*256 + co) = v;
  }
}

// K2 v6 (MFMA): v3's 128-px LDS-staged row tile + 512 threads (8 waves:
// 2 pixel-halves x 4 channel-groups). Same bytes/tiles as v3 (59us), double
// the in-flight waves (16/CU). Fused GN1 stats + subsampled resS output.
// grid (128, 8) x 512 threads. LDS ~69KB -> 2 blocks/CU.
__global__ __launch_bounds__(512,4)
void k2_mfma(const bf16* __restrict__ zT, const bf16* __restrict__ Wub,
             const float* __restrict__ g2, const float* __restrict__ b2,
             const float* __restrict__ resm, const float* __restrict__ resn,
             bf16* __restrict__ resS, float* __restrict__ gsum1, float* __restrict__ gssq1){
  __shared__ bf16 zt[128*264];     // 67.6KB; reused as output staging after MFMA
  __shared__ float rm_s[256];
  __shared__ float gn_s[32], gn_q[32];
  int b = blockIdx.y;
  int h = blockIdx.x;              // tile = full row h (w = 0..127)
  int p0 = h << 7;
  int t = threadIdx.x;
  if(t < 32){ gn_s[t] = 0.f; gn_q[t] = 0.f; }
  if(t >= 64 && t < 128){
    int tt = t - 64;
    *(f32x4_t*)&rm_s[tt*4] = *(const f32x4_t*)(resm + ((size_t)b*128 + h)*256 + tt*4);
  }
  // stage 128px x 256ch (64KB) into LDS, fully coalesced (512 thr x 8 iters)
  {
    const short* src = (const short*)zT + (((size_t)b*16384 + p0)*256);
    #pragma unroll
    for(int i=0;i<8;i++){
      int slot = t + i*512;          // 4096 slots (128 rows x 32)
      int p = slot >> 5;
      int cc = (slot & 31)*8;
      short8_t v = *(const short8_t*)(src + (size_t)p*256 + cc);
      *(short8_t*)&zt[p*264 + cc] = v;
    }
  }
  __syncthreads();
  int wv = t>>6, lane = t&63, quad = lane>>4, l16 = lane&15;
  int ph = wv >> 2;                // pixel half (0: w 0-63, 1: w 64-127)
  int m0 = (wv & 3)*64;            // channel group
  int px0 = ph*64;
  f32x4_t acc[4][4];
  #pragma unroll
  for(int ms=0;ms<4;ms++)
    #pragma unroll
    for(int ns=0;ns<4;ns++) acc[ms][ns] = (f32x4_t){0.f,0.f,0.f,0.f};
  const short* wp = (const short*)Wub + (size_t)(m0 + l16)*256 + quad*8;
  short8_t afr[4];
  #pragma unroll
  for(int ms=0;ms<4;ms++) afr[ms] = *(const short8_t*)(wp + (size_t)ms*16*256);
  for(int k0=0;k0<256;k0+=32){
    short8_t anext[4];
    if(k0 + 32 < 256){
      #pragma unroll
      for(int ms=0;ms<4;ms++)
        anext[ms] = *(const short8_t*)(wp + (size_t)ms*16*256 + k0 + 32);
    }
    short8_t bfr[4];
    #pragma unroll
    for(int ns=0;ns<4;ns++)
      bfr[ns] = *(const short8_t*)&zt[(px0 + ns*16 + l16)*264 + k0 + quad*8];
    #pragma unroll
    for(int ms=0;ms<4;ms++)
      #pragma unroll
      for(int ns=0;ns<4;ns++)
        acc[ms][ns] = __builtin_amdgcn_mfma_f32_16x16x32_bf16(afr[ms], bfr[ns], acc[ms][ns], 0,0,0);
    #pragma unroll
    for(int ms=0;ms<4;ms++) afr[ms] = anext[ms];
  }
  __syncthreads();       // all waves done reading zt; reuse as output staging
  bool h_even = ((h & 1) == 0);
  float sg[4], qg[4];
  #pragma unroll
  for(int ms=0;ms<4;ms++){ sg[ms]=0.f; qg[ms]=0.f; }
  #pragma unroll
  for(int ns=0;ns<4;ns++){
    int pl = px0 + ns*16 + l16;      // local pixel = w (0..127)
    const float* rn = resn + ((size_t)b*128 + pl)*256;
    bool store = h_even && ((pl & 1) == 0);
    #pragma unroll
    for(int ms=0;ms<4;ms++){
      int o = m0 + ms*16 + quad*4;
      f32x4_t a = acc[ms][ns];
      f32x4_t gv = *(const f32x4_t*)(g2+o);
      f32x4_t bv = *(const f32x4_t*)(b2+o);
      f32x4_t rmv = *(const f32x4_t*)&rm_s[o];
      f32x4_t rnv = *(const f32x4_t*)(rn+o);
      alignas(8) bf16 ov[4];
      #pragma unroll
      for(int r=0;r<4;r++){
        float zv = a[r]*(gv[r]*BNSC) + bv[r];
        zv = fminf(fmaxf(zv, 0.f), 6.f);
        float gate = fminf(fmaxf(rmv[r]+rnv[r]+3.f, 0.f), 6.f)*(1.f/6.f);
        float vo = zv*gate;
        ov[r] = f2bf(vo);
        sg[ms] += vo;
        qg[ms] += vo*vo;
      }
      if(store) *(short4_t*)&zt[(pl>>1)*264 + o] = *(const short4_t*)ov;
    }
  }
  // GN1 partial sums: reduce over l16 lanes (pixel axis), then LDS per-group accum
  #pragma unroll
  for(int ms=0;ms<4;ms++){
    float S = sg[ms], Q = qg[ms];
    S += __shfl_xor(S, 1, 64);  Q += __shfl_xor(Q, 1, 64);
    S += __shfl_xor(S, 2, 64);  Q += __shfl_xor(Q, 2, 64);
    S += __shfl_xor(S, 4, 64);  Q += __shfl_xor(Q, 4, 64);
    S += __shfl_xor(S, 8, 64);  Q += __shfl_xor(Q, 8, 64);
    if(l16 == 0){
      int o = m0 + ms*16 + quad*4;   // 4 consecutive channels, same group o>>3
      atomicAdd(&gn_s[o>>3], S);
      atomicAdd(&gn_q[o>>3], Q);
    }
  }
  __syncthreads();
  if(t < 32){
    atomicAdd(&gsum1[b*32 + t], gn_s[t]);
    atomicAdd(&gssq1[b*32 + t], gn_q[t]);
  }
  // stream out (even h only): 64 even-w pixels -> contiguous 32KB burst
  if(h_even){
    short* dst = (short*)resS + ((size_t)b*4096 + (h>>1)*64)*256;
    #pragma unroll
    for(int it=0; it<4; it++){
      int slot = t + it*512;          // 2048 slots (64 rows x 32)
      int row = slot >> 5;            // ps row 0..63 (w = 2*row)
      int co = (slot & 31)*8;
      short8_t v = *(const short8_t*)&zt[row*264 + co];
      *(short8_t*)(dst + (size_t)row*256 + co) = v;
    }
  }
}

// K4 v4 (MFMA): 64-px tile (grid 64x8 -> 512 blocks, ~4 blocks/CU), reads compact
// resS, inline GN1 finalize, per-channel (sum, ssq, cross-with-x) stats.
__global__ __launch_bounds__(256,4)
void k4_mfma(const bf16* __restrict__ resS, const bf16* __restrict__ Wdb,
             const float* __restrict__ gsum1, const float* __restrict__ gssq1,
             const float* __restrict__ gng, const float* __restrict__ gnb,
             const float* __restrict__ dbg, const float* __restrict__ dbb,
             const float* __restrict__ x, float* __restrict__ t1,
             float* __restrict__ t1s, float* __restrict__ t1q, float* __restrict__ t1x){
  __shared__ bf16 at[64*264];
  __shared__ float sc[256], sb[256];
  __shared__ float stm[32], str[32];
  int b = blockIdx.y;
  int q0 = blockIdx.x*64;
  int t = threadIdx.x;
  if(t < 32){
    float m = gsum1[b*32+t] * (1.f/131072.f);
    float var = gssq1[b*32+t] * (1.f/131072.f) - m*m;
    stm[t] = m;
    str[t] = rsqrtf(var + EPSV);
  }
  __syncthreads();
  {
    int cch = t, g = cch>>3;
    float m = stm[g], rs = str[g];
    float s = rs*gng[cch];
    sc[cch] = s; sb[cch] = gnb[cch] - m*s;
  }
  __syncthreads();
  {
    int pr = t>>5;
    int cc = (t&31)*8;
    const short* src = (const short*)resS + ((size_t)b*4096 + q0)*256;
    #pragma unroll
    for(int i=0;i<8;i++){
      int q = pr + i*8;
      short8_t v = *(const short8_t*)(src + (size_t)q*256 + cc);
      const bf16* vv = (const bf16*)&v;
      alignas(16) bf16 ov[8];
      #pragma unroll
      for(int j=0;j<8;j++) ov[j] = f2bf(bf2f(vv[j])*sc[cc+j] + sb[cc+j]);
      *(short8_t*)&at[q*264 + cc] = *(const short8_t*)ov;
    }
  }
  __syncthreads();
  int wv = t>>6, lane = t&63, quad = lane>>4, l16 = lane&15;
  int n0 = wv*64;
  f32x4_t acc[4][4];
  #pragma unroll
  for(int ms=0;ms<4;ms++)
    #pragma unroll
    for(int ns=0;ns<4;ns++) acc[ms][ns] = (f32x4_t){0.f,0.f,0.f,0.f};
  const short* wp = (const short*)Wdb + (size_t)(n0 + l16)*256 + quad*8;
  short8_t bfr[4];
  #pragma unroll
  for(int ns=0;ns<4;ns++) bfr[ns] = *(const short8_t*)(wp + (size_t)ns*16*256);
  for(int k0=0;k0<256;k0+=32){
    short8_t bnext[4];
    if(k0 + 32 < 256){
      #pragma unroll
      for(int ns=0;ns<4;ns++)
        bnext[ns] = *(const short8_t*)(wp + (size_t)ns*16*256 + k0 + 32);
    }
    short8_t afr[4];
    #pragma unroll
    for(int ms=0;ms<4;ms++)
      afr[ms] = *(const short8_t*)&at[(ms*16 + l16)*264 + k0 + quad*8];
    #pragma unroll
    for(int ms=0;ms<4;ms++)
      #pragma unroll
      for(int ns=0;ns<4;ns++)
        acc[ms][ns] = __builtin_amdgcn_mfma_f32_16x16x32_bf16(afr[ms], bfr[ns], acc[ms][ns], 0,0,0);
    #pragma unroll
    for(int ns=0;ns<4;ns++) bfr[ns] = bnext[ns];
  }
  #pragma unroll
  for(int ns=0;ns<4;ns++){
    int o = n0 + ns*16 + l16;
    float s2 = dbg[o]*BNSC, bb2 = dbb[o];
    float* dst = t1 + (((size_t)b*256 + o) << 12);
    const float* xsrc = x + (((size_t)b*256 + o) << 12);
    float s_=0.f, q_=0.f, c_=0.f;
    #pragma unroll
    for(int ms=0;ms<4;ms++){
      int ps = q0 + ms*16 + quad*4;
      f32x4_t a = acc[ms][ns];
      f32x4_t xv = *(const f32x4_t*)(xsrc + ps);
      f32x4_t ov;
      #pragma unroll
      for(int r=0;r<4;r++){
        ov[r] = a[r]*s2 + bb2;
        s_ += ov[r];
        q_ += ov[r]*ov[r];
        c_ += ov[r]*xv[r];
      }
      *(f32x4_t*)(dst + ps) = ov;
    }
    // reduce over quads (pixel axis) only -> per-channel partials
    s_ += __shfl_xor(s_, 16, 64);
    q_ += __shfl_xor(q_, 16, 64);
    c_ += __shfl_xor(c_, 16, 64);
    s_ += __shfl_xor(s_, 32, 64);
    q_ += __shfl_xor(q_, 32, 64);
    c_ += __shfl_xor(c_, 32, 64);
    if(quad == 0){
      atomicAdd(&t1s[b*256 + o], s_);
      atomicAdd(&t1q[b*256 + o], q_);
      atomicAdd(&t1x[b*256 + o], c_);
    }
  }
}

// compose: per-(b,c) affine coefficients for out = A*t1 + B*x + C  (gn3(gn2(t1)+x))
__global__ void compose_gn(const float* __restrict__ t1s, const float* __restrict__ t1q,
                           const float* __restrict__ t1x, const float* __restrict__ xs,
                           const float* __restrict__ xq, const float* __restrict__ gng,
                           const float* __restrict__ gnb,
                           float* __restrict__ cA, float* __restrict__ cB, float* __restrict__ cC){
  int b = blockIdx.x, c = threadIdx.x;
  int i = b*256 + c;
  float ts = t1s[i], tq = t1q[i], tx = t1x[i];
  float sx = xs[i], qx = xq[i];
  // GN2 group stats (8 consecutive channels per group; lanes 8k..8k+7)
  float gs = ts, gq = tq;
  gs += __shfl_xor(gs,1,64); gq += __shfl_xor(gq,1,64);
  gs += __shfl_xor(gs,2,64); gq += __shfl_xor(gq,2,64);
  gs += __shfl_xor(gs,4,64); gq += __shfl_xor(gq,4,64);
  float m2 = gs*(1.f/32768.f);
  float v2 = gq*(1.f/32768.f) - m2*m2;
  float rs2 = rsqrtf(v2 + EPSV);
  float a  = rs2*gng[c];
  float bb = gnb[c] - m2*a;
  // u = a*t1 + bb + x ; per-channel stats of u
  float Su = a*ts + 4096.f*bb + sx;
  float Qu = a*a*tq + 4096.f*bb*bb + qx + 2.f*a*bb*ts + 2.f*a*tx + 2.f*bb*sx;
  float gSu = Su, gQu = Qu;
  gSu += __shfl_xor(gSu,1,64); gQu += __shfl_xor(gQu,1,64);
  gSu += __shfl_xor(gSu,2,64); gQu += __shfl_xor(gQu,2,64);
  gSu += __shfl_xor(gSu,4,64); gQu += __shfl_xor(gQu,4,64);
  float m3 = gSu*(1.f/32768.f);
  float v3 = gQu*(1.f/32768.f) - m3*m3;
  float rs3 = rsqrtf(v3 + EPSV);
  float s3 = rs3*gng[c];
  cA[i] = a*s3;
  cB[i] = s3;
  cC[i] = (bb - m3)*s3 + gnb[c];
}

// K8 v2 (float4): out = A*t1 + B*x + C   (replaces k6+k8)
__global__ void k8_gn_out(const float* __restrict__ t1, const float* __restrict__ x,
                          const float* __restrict__ cA, const float* __restrict__ cB,
                          const float* __restrict__ cC, float* __restrict__ out){
  int i4 = blockIdx.x*256 + threadIdx.x;
  int idx = i4 << 2;
  int c = (idx >> 12) & 255, b = idx >> 20;
  int i = b*256 + c;
  float A = cA[i], Bv = cB[i], C = cC[i];
  f32x4_t tv = *(const f32x4_t*)(t1 + idx);
  f32x4_t xv = *(const f32x4_t*)(x + idx);
  f32x4_t ov;
  #pragma unroll
  for(int r=0;r<4;r++) ov[r] = A*tv[r] + Bv*xv[r] + C;
  *(f32x4_t*)(out + idx) = ov;
}

extern "C" void kernel_launch(void* const* d_in, const int* in_sizes, int n_in,
                              void* d_out, int out_size, void* d_ws, size_t ws_size,
                              hipStream_t stream){
  const float* x      = (const float*)d_in[0];
  const float* pos    = (const float*)d_in[1];
  const float* ln_g   = (const float*)d_in[2];
  const float* ln_b   = (const float*)d_in[3];
  const float* in_w   = (const float*)d_in[4];
  const float* conv_w = (const float*)d_in[5];
  const float* conv_b = (const float*)d_in[6];
  const float* xproj  = (const float*)d_in[7];
  const float* dt_w   = (const float*)d_in[8];
  const float* dt_b   = (const float*)d_in[9];
  const float* A_log  = (const float*)d_in[10];
  const float* Dp     = (const float*)d_in[11];
  const float* out_w  = (const float*)d_in[12];
  const float* proj_w = (const float*)d_in[13];
  const float* proj_b = (const float*)d_in[14];
  const float* dw_w   = (const float*)d_in[15];
  const float* bn1g   = (const float*)d_in[16];
  const float* bn1b   = (const float*)d_in[17];
  const float* pw_w   = (const float*)d_in[18];
  const float* bn2g   = (const float*)d_in[19];
  const float* bn2b   = (const float*)d_in[20];
  const float* dpw_w  = (const float*)d_in[21];
  const float* dbng   = (const float*)d_in[22];
  const float* dbnb   = (const float*)d_in[23];
  const float* gng    = (const float*)d_in[24];
  const float* gnb    = (const float*)d_in[25];
  float* out = (float*)d_out;

  float* ws = (float*)d_ws;
  bf16*  resS = (bf16*)ws;                       // compact subsampled (b,4096,256), 16MB
  bf16*  zT   = (bf16*)(ws + 16777216);          // pixel-major (b,p,c), 64MB
  float* scanP = ws + 16777216;                  // overlay of zT region
  float* scanH = ws + 16777216 + 2097152;
  float* zone = ws + 33554432;
  float* xz   = zone;                            // 4,194,304
  float* xc   = xz  + 4194304;                   // 2,097,152
  float* dbl  = xc  + 2097152;                   //   196,608
  float* dtb  = dbl + 196608;                    // 2,097,152
  bf16*  ybb  = (bf16*)(dtb + 2097152);          // 1,048,576 f worth
  bf16*  xcb  = (bf16*)(dtb + 2097152 + 524288); // 1,048,576 f worth (2M bf16)
  float* t1   = zone;                            // overlay (first 8,388,608)
  float* mo   = zone + 9633792;                  // 1,048,576
  float* resm = mo   + 1048576;
  float* resn = resm + 262144;
  float* pmax = resn + 262144;
  float* pmin = pmax + 262144;
  float* PT   = pmin + 262144;
  bf16*  ubmax= (bf16*)(PT + 131072);
  bf16*  ubmin= (bf16*)(PT + 131072 + 131072);
  bf16*  Winb = (bf16*)(PT + 131072 + 262144);
  bf16*  Woutb= (bf16*)(PT + 131072 + 524288);
  bf16*  Wub  = (bf16*)(PT + 131072 + 655360);
  bf16*  Wdb  = (bf16*)(PT + 131072 + 688128);
  bf16*  Wxpb = (bf16*)(PT + 131072 + 720896);   // 49152 bf16 = 24576 floats
  float* gacc = PT + 131072 + 745472;
  float* gsum1 = gacc,        *gssq1 = gacc + 256;
  float* t1s = gacc + 512;
  float* t1q = gacc + 2560;
  float* t1x = gacc + 4608;
  float* xs  = gacc + 6656;
  float* xq  = gacc + 8704;
  float* cA  = gacc + 10752;
  float* cB  = gacc + 12800;
  float* cC  = gacc + 14848;

  prep_weights<<<4288,256,0,stream>>>(in_w, out_w, pw_w, dpw_w, proj_w, xproj,
                                      Winb, Woutb, Wub, Wdb, Wxpb, PT, gacc);

  r1_reduce_pe<<<2048,256,0,stream>>>(x, pos, pmax, pmin, xs, xq);
  ln_rows2<<<2048,256,0,stream>>>(pmax, pmin, ln_g, ln_b, ubmax, ubmin);

  m1_mfma<<<256,256,0,stream>>>(ubmax, ubmin, Winb, xz);
  m2_conv<<<2048,256,0,stream>>>(xz, conv_w, conv_b, xc, xcb);
  m3_xproj<<<64,256,0,stream>>>(xcb, Wxpb, dbl);
  m4_dt<<<2048,256,0,stream>>>(dbl, dt_w, dt_b, dtb);
  m5_passA<<<512,256,0,stream>>>(dtb, xc, dbl, A_log, scanP, scanH);
  m5_passB<<<512,256,0,stream>>>(dtb, xc, dbl, xz, A_log, Dp, scanP, scanH, ybb);
  m6_mfma<<<64,256,0,stream>>>(ybb, Woutb, ln_g, ln_b, mo);
  m7_proj<<<128,256,0,stream>>>(mo, PT, proj_b, ln_g, ln_b, resm, resn);

  k1_deconv_T<<<8192,256,0,stream>>>(x, dw_w, bn1g, bn1b, zT);
  k2_mfma<<<dim3(128,8),512,0,stream>>>(zT, Wub, bn2g, bn2b, resm, resn, resS,
                                        gsum1, gssq1);

  k4_mfma<<<dim3(64,8),256,0,stream>>>(resS, Wdb, gsum1, gssq1,
                                       gng, gnb, dbng, dbnb, x, t1, t1s, t1q, t1x);

  compose_gn<<<8,256,0,stream>>>(t1s, t1q, t1x, xs, xq, gng, gnb, cA, cB, cC);
  k8_gn_out<<<8192,256,0,stream>>>(t1, x, cA, cB, cC, out);
}

// Round 10
// 462.958 us; speedup vs baseline: 1.0681x; 1.0297x over previous
//
#include <hip/hip_runtime.h>
#include <hip/hip_bf16.h>
#include <math.h>

typedef __hip_bfloat16 bf16;
typedef __attribute__((ext_vector_type(8))) short short8_t;
typedef __attribute__((ext_vector_type(4))) short short4_t;
typedef __attribute__((ext_vector_type(4))) float f32x4_t;

#define EPSV 1e-5f
#define BNSC 0.99999500003749968f  // 1/sqrt(1+1e-5)

__device__ __forceinline__ float bf2f(bf16 v){ return __bfloat162float(v); }
__device__ __forceinline__ bf16 f2bf(float v){ return __float2bfloat16(v); }

__device__ __forceinline__ float blk_sum(float v, float* sm){
  int tid = threadIdx.x;
  #pragma unroll
  for(int o=32;o>0;o>>=1) v += __shfl_down(v, o, 64);
  if((tid&63)==0) sm[tid>>6] = v;
  __syncthreads();
  float s = 0.f;
  int nw = blockDim.x>>6;
  for(int i=0;i<nw;i++) s += sm[i];
  __syncthreads();
  return s;
}

__device__ __forceinline__ float softplusf(float x){
  return (x > 20.f) ? x : __logf(1.f + __expf(x));
}
__device__ __forceinline__ float siluf(float x){
  return x / (1.f + __expf(-x));
}

// one-shot prep: bf16 converts (incl xproj) + proj transpose + zero stat accumulators
__global__ void prep_weights(const float* __restrict__ in_w, const float* __restrict__ out_w,
                             const float* __restrict__ pw_w, const float* __restrict__ dpw_w,
                             const float* __restrict__ proj_w, const float* __restrict__ xproj_w,
                             bf16* __restrict__ Winb, bf16* __restrict__ Woutb,
                             bf16* __restrict__ Wub, bf16* __restrict__ Wdb,
                             bf16* __restrict__ Wxpb, float* __restrict__ PT,
                             float* __restrict__ gacc){
  int idx = blockIdx.x*256 + threadIdx.x;      // < 1,097,728
  if(idx < 6656) gacc[idx] = 0.f;              // gsum1/gssq1 + t1s/t1q/t1x
  if(idx < 524288){ Winb[idx] = f2bf(in_w[idx]); return; }
  if(idx < 786432){ int i=idx-524288; Woutb[i] = f2bf(out_w[i]); return; }
  if(idx < 851968){ int i=idx-786432; Wub[i] = f2bf(pw_w[i]); return; }
  if(idx < 917504){ int i=idx-851968; Wdb[i] = f2bf(dpw_w[i]); return; }
  if(idx < 1048576){
    int k = idx - 917504;                      // < 131072
    int i = k >> 9, j = k & 511;
    PT[j*256 + i] = proj_w[k];
    return;
  }
  int i = idx - 1048576;                       // < 49152
  Wxpb[i] = f2bf(xproj_w[i]);
}

// R1 (256 threads): load x slice coalesced; wave0 = col reduce, wave1 = row reduce
// + per-(b,c) sum/ssq of x for the fused GN3 composition
__global__ __launch_bounds__(256)
void r1_reduce_pe(const float* __restrict__ x, const float* __restrict__ pe,
                  float* __restrict__ pmax, float* __restrict__ pmin,
                  float* __restrict__ xs, float* __restrict__ xq){
  __shared__ float tile[64*65];
  __shared__ float rs_[4], rq_[4];
  int bc = blockIdx.x;          // b*256 + c
  int b = bc >> 8, c = bc & 255;
  const float* xp = x + ((size_t)bc << 12);
  float s = 0.f, q = 0.f;
  for(int i=threadIdx.x; i<4096; i+=256){
    float v = xp[i];
    tile[(i>>6)*65 + (i&63)] = v;
    s += v; q += v*v;
  }
  #pragma unroll
  for(int o=32;o>0;o>>=1){ s += __shfl_down(s, o, 64); q += __shfl_down(q, o, 64); }
  int wv = threadIdx.x >> 6, t = threadIdx.x & 63;
  if(t == 0){ rs_[wv] = s; rq_[wv] = q; }
  __syncthreads();
  if(threadIdx.x == 0){
    xs[bc] = rs_[0]+rs_[1]+rs_[2]+rs_[3];
    xq[bc] = rq_[0]+rq_[1]+rq_[2]+rq_[3];
  }
  if(wv >= 2) return;
  float coords = fmaxf((t + 0.5f)*0.25f - 0.5f, 0.f);
  int i0 = (int)floorf(coords);
  int i1 = min(i0+1, 15);
  float wg = coords - (float)i0;
  float pos = pe[c*16+i0]*(1.f-wg) + pe[c*16+i1]*wg;
  if(wv == 0){
    float cmx=-3.4e38f, cmn=3.4e38f; int cax=0, can=0;
    for(int h=0;h<64;h++){
      float v = tile[h*65 + t];
      if(v > cmx){ cmx=v; cax=h; }
      if(v < cmn){ cmn=v; can=h; }
    }
    size_t base_col = ((size_t)b*128 + t)*256 + c;
    pmax[base_col] = cmx + pos + (float)cax;
    pmin[base_col] = cmn + pos + (float)can;
  } else {
    float rmx=-3.4e38f, rmn=3.4e38f; int rax=0, ran=0;
    for(int w=0;w<64;w++){
      float v = tile[t*65 + w];
      if(v > rmx){ rmx=v; rax=w; }
      if(v < rmn){ rmn=v; ran=w; }
    }
    size_t base_row = ((size_t)b*128 + 64 + t)*256 + c;
    pmax[base_row] = rmx + pos + (float)rax;
    pmin[base_row] = rmn + pos + (float)ran;
  }
}

// paired LN over 256: rows<1024 -> A, else B; writes f32 back + bf16 copy
__global__ void ln_rows2(float* __restrict__ bufA, float* __restrict__ bufB,
                         const float* __restrict__ g, const float* __restrict__ bb,
                         bf16* __restrict__ boutA, bf16* __restrict__ boutB){
  __shared__ float sm[8];
  int row = blockIdx.x, t = threadIdx.x;
  float* buf; bf16* bout;
  if(row < 1024){ buf = bufA; bout = boutA; }
  else { buf = bufB; bout = boutB; row -= 1024; }
  float v = buf[(size_t)row*256 + t];
  float m = blk_sum(v, sm) * (1.f/256.f);
  float dv = v - m;
  float var = blk_sum(dv*dv, sm) * (1.f/256.f);
  float r = dv * rsqrtf(var + EPSV) * g[t] + bb[t];
  buf[(size_t)row*256 + t] = r;
  if(bout) bout[(size_t)row*256 + t] = f2bf(r);
}

// M1 (MFMA): xz[rb][l][i] = sum_c u_bf(b,l_eff,c) * in_w_bf[d][i][c]
__global__ __launch_bounds__(256,2)
void m1_mfma(const bf16* __restrict__ ubmax, const bf16* __restrict__ ubmin,
             const bf16* __restrict__ Win, float* __restrict__ xz){
  __shared__ bf16 att[64*264];
  int bx = blockIdx.x;
  int it = bx & 3, lt = (bx>>2)&1, b = (bx>>3)&7, r = bx>>6;
  int d = r & 1;
  const bf16* u = (r < 2) ? ubmax : ubmin;
  int flip = r & 1;
  int t = threadIdx.x;
  {
    int pr = t>>5, cc = (t&31)*8;
    #pragma unroll
    for(int i=0;i<8;i++){
      int p = pr + i*8;
      int l = lt*64 + p;
      int le = flip ? (127 - l) : l;
      short8_t v = *(const short8_t*)((const short*)u + ((size_t)(b*128 + le))*256 + cc);
      *(short8_t*)&att[p*264 + cc] = v;
    }
  }
  __syncthreads();
  int wv = t>>6, lane = t&63, quad = lane>>4, l16 = lane&15;
  int m0 = wv*64;
  f32x4_t acc[4][4];
  #pragma unroll
  for(int ms=0;ms<4;ms++)
    #pragma unroll
    for(int ns=0;ns<4;ns++) acc[ms][ns] = (f32x4_t){0.f,0.f,0.f,0.f};
  const short* wbase = (const short*)Win + ((size_t)d*1024 + it*256)*256;
  for(int k0=0;k0<256;k0+=32){
    short8_t afr[4], bfr[4];
    #pragma unroll
    for(int ms=0;ms<4;ms++)
      afr[ms] = *(const short8_t*)(wbase + (size_t)(m0 + ms*16 + l16)*256 + k0 + quad*8);
    #pragma unroll
    for(int ns=0;ns<4;ns++)
      bfr[ns] = *(const short8_t*)&att[(ns*16 + l16)*264 + k0 + quad*8];
    #pragma unroll
    for(int ms=0;ms<4;ms++)
      #pragma unroll
      for(int ns=0;ns<4;ns++)
        acc[ms][ns] = __builtin_amdgcn_mfma_f32_16x16x32_bf16(afr[ms], bfr[ns], acc[ms][ns], 0,0,0);
  }
  int rb = r*8 + b;
  #pragma unroll
  for(int ns=0;ns<4;ns++){
    int l = lt*64 + ns*16 + l16;
    float* dst = xz + ((size_t)rb*128 + l)*1024 + it*256;
    #pragma unroll
    for(int ms=0;ms<4;ms++){
      int i = m0 + ms*16 + quad*4;
      *(f32x4_t*)(dst + i) = acc[ms][ns];
    }
  }
}

// M2: conv (D_CONV=4 causal) + silu, streaming f32x4; writes xc (f32) + xcb (bf16)
__global__ __launch_bounds__(256)
void m2_conv(const float* __restrict__ xz, const float* __restrict__ cw,
             const float* __restrict__ cb, float* __restrict__ xc,
             bf16* __restrict__ xcb){
  int i4 = blockIdx.x*256 + threadIdx.x;   // < 524288
  int idx = i4 << 2;                        // element in [4096][512]
  int row = idx >> 9, dd = idx & 511;
  int gl = row & 127;
  int d = (row >> 10) & 1;
  const float* src = xz + (size_t)row*1024 + dd;
  const float* cwp = cw + (size_t)(d*512 + dd)*4;
  f32x4_t w0 = *(const f32x4_t*)(cwp);      // weights for dd+0 (k=0..3)
  f32x4_t w1 = *(const f32x4_t*)(cwp+4);
  f32x4_t w2 = *(const f32x4_t*)(cwp+8);
  f32x4_t w3 = *(const f32x4_t*)(cwp+12);
  f32x4_t bias = *(const f32x4_t*)(cb + d*512 + dd);
  f32x4_t z4 = (f32x4_t){0.f,0.f,0.f,0.f};
  f32x4_t t3 = *(const f32x4_t*)(src);
  f32x4_t t2 = (gl>=1) ? *(const f32x4_t*)(src-1024) : z4;
  f32x4_t t1 = (gl>=2) ? *(const f32x4_t*)(src-2048) : z4;
  f32x4_t t0 = (gl>=3) ? *(const f32x4_t*)(src-3072) : z4;
  f32x4_t o;
  o[0] = bias[0] + t0[0]*w0[0] + t1[0]*w0[1] + t2[0]*w0[2] + t3[0]*w0[3];
  o[1] = bias[1] + t0[1]*w1[0] + t1[1]*w1[1] + t2[1]*w1[2] + t3[1]*w1[3];
  o[2] = bias[2] + t0[2]*w2[0] + t1[2]*w2[1] + t2[2]*w2[2] + t3[2]*w2[3];
  o[3] = bias[3] + t0[3]*w3[0] + t1[3]*w3[1] + t2[3]*w3[2] + t3[3]*w3[3];
  alignas(8) bf16 ob[4];
  #pragma unroll
  for(int r=0;r<4;r++){ o[r] = siluf(o[r]); ob[r] = f2bf(o[r]); }
  *(f32x4_t*)(xc + idx) = o;
  *(short4_t*)((short*)xcb + idx) = *(const short4_t*)ob;
}

// M3 (MFMA): dbl[4096][48] = xcb[4096][512] x Wxpb[48][512]^T. 64 blocks x 4 waves.
__global__ __launch_bounds__(256)
void m3_xproj(const bf16* __restrict__ xcb, const bf16* __restrict__ Wxpb,
              float* __restrict__ dbl){
  int r0 = blockIdx.x * 64;
  int d = (r0 >> 10) & 1;
  int t = threadIdx.x;
  int wv = t>>6, lane = t&63, quad = lane>>4, l16 = lane&15;
  int rowl = wv*16 + l16;
  const short* bbase = (const short*)xcb + (size_t)(r0 + rowl)*512;
  const short* abase = (const short*)Wxpb + (size_t)d*48*512;
  f32x4_t acc[3];
  #pragma unroll
  for(int ms=0;ms<3;ms++) acc[ms] = (f32x4_t){0.f,0.f,0.f,0.f};
  #pragma unroll 4
  for(int k0=0;k0<512;k0+=32){
    short8_t bfr = *(const short8_t*)(bbase + k0 + quad*8);
    short8_t afr[3];
    #pragma unroll
    for(int ms=0;ms<3;ms++)
      afr[ms] = *(const short8_t*)(abase + (size_t)(ms*16 + l16)*512 + k0 + quad*8);
    #pragma unroll
    for(int ms=0;ms<3;ms++)
      acc[ms] = __builtin_amdgcn_mfma_f32_16x16x32_bf16(afr[ms], bfr, acc[ms], 0,0,0);
  }
  float* dst = dbl + (size_t)(r0 + rowl)*48;
  #pragma unroll
  for(int ms=0;ms<3;ms++)
    *(f32x4_t*)(dst + ms*16 + quad*4) = acc[ms];
}

// M4: dt = softplus(dbl[:, :16] . dtw^T + bias), streaming f32x4
__global__ __launch_bounds__(256)
void m4_dt(const float* __restrict__ dbl, const float* __restrict__ dtw,
           const float* __restrict__ dtbias, float* __restrict__ dt){
  int i4 = blockIdx.x*256 + threadIdx.x;   // < 524288
  int idx = i4 << 2;
  int row = idx >> 9, dd = idx & 511;
  int d = (row >> 10) & 1;
  const float* dr = dbl + (size_t)row*48;
  f32x4_t dr0 = *(const f32x4_t*)(dr);
  f32x4_t dr1 = *(const f32x4_t*)(dr+4);
  f32x4_t dr2 = *(const f32x4_t*)(dr+8);
  f32x4_t dr3 = *(const f32x4_t*)(dr+12);
  f32x4_t bias = *(const f32x4_t*)(dtbias + d*512 + dd);
  f32x4_t o;
  #pragma unroll
  for(int j=0;j<4;j++){
    const float* wp = dtw + (size_t)(d*512 + dd + j)*16;
    f32x4_t w0 = *(const f32x4_t*)(wp);
    f32x4_t w1 = *(const f32x4_t*)(wp+4);
    f32x4_t w2 = *(const f32x4_t*)(wp+8);
    f32x4_t w3 = *(const f32x4_t*)(wp+12);
    float s = bias[j];
    s += dr0[0]*w0[0] + dr0[1]*w0[1] + dr0[2]*w0[2] + dr0[3]*w0[3];
    s += dr1[0]*w1[0] + dr1[1]*w1[1] + dr1[2]*w1[2] + dr1[3]*w1[3];
    s += dr2[0]*w2[0] + dr2[1]*w2[1] + dr2[2]*w2[2] + dr2[3]*w2[3];
    s += dr3[0]*w3[0] + dr3[1]*w3[1] + dr3[2]*w3[2] + dr3[3]*w3[3];
    o[j] = softplusf(s);
  }
  *(f32x4_t*)(dt + idx) = o;
}

// M5a: chunked scan pass A
__global__ void m5_passA(const float* __restrict__ dt, const float* __restrict__ xc,
                         const float* __restrict__ dbl, const float* __restrict__ Alog,
                         float* __restrict__ P, float* __restrict__ Hl){
  int bx = blockIdx.x;
  int seg = bx & 7, half = (bx>>3)&1, rb = bx>>4;
  int dd = half*256 + threadIdx.x;
  int d = (rb>>3)&1;
  float A[16], h[16], pr[16];
  #pragma unroll
  for(int s=0;s<16;s++){
    A[s] = -__expf(Alog[(size_t)(d*512 + dd)*16 + s]);
    h[s] = 0.f; pr[s] = 1.f;
  }
  int l0 = seg*16;
  for(int l=l0;l<l0+16;l++){
    size_t row = (size_t)rb*128 + l;
    float dtv = dt[row*512 + dd];
    float xcv = xc[row*512 + dd];
    float bx_ = dtv*xcv;
    const float* dr = dbl + row*48;
    #pragma unroll
    for(int s=0;s<16;s++){
      float dA = __expf(dtv*A[s]);
      pr[s] *= dA;
      h[s] = dA*h[s] + bx_*dr[16+s];
    }
  }
  size_t o = ((size_t)(rb*8 + seg)*512 + dd)*16;
  #pragma unroll
  for(int s=0;s<16;s+=4){
    *(f32x4_t*)(P  + o + s) = (f32x4_t){pr[s],pr[s+1],pr[s+2],pr[s+3]};
    *(f32x4_t*)(Hl + o + s) = (f32x4_t){h[s],h[s+1],h[s+2],h[s+3]};
  }
}

// M5b: combine prefix, re-scan, emit y
__global__ void m5_passB(const float* __restrict__ dt, const float* __restrict__ xc,
                         const float* __restrict__ dbl, const float* __restrict__ xz,
                         const float* __restrict__ Alog, const float* __restrict__ Dp,
                         const float* __restrict__ P, const float* __restrict__ Hl,
                         bf16* __restrict__ ybb){
  int bx = blockIdx.x;
  int seg = bx & 7, half = (bx>>3)&1, rb = bx>>4;
  int dd = half*256 + threadIdx.x;
  int d = (rb>>3)&1;
  float A[16], h[16];
  #pragma unroll
  for(int s=0;s<16;s++){
    A[s] = -__expf(Alog[(size_t)(d*512 + dd)*16 + s]);
    h[s] = 0.f;
  }
  for(int j=0;j<seg;j++){
    size_t o = ((size_t)(rb*8 + j)*512 + dd)*16;
    #pragma unroll
    for(int s=0;s<16;s+=4){
      f32x4_t pv = *(const f32x4_t*)(P + o + s);
      f32x4_t hv = *(const f32x4_t*)(Hl + o + s);
      h[s]   = pv[0]*h[s]   + hv[0];
      h[s+1] = pv[1]*h[s+1] + hv[1];
      h[s+2] = pv[2]*h[s+2] + hv[2];
      h[s+3] = pv[3]*h[s+3] + hv[3];
    }
  }
  float Dv = Dp[d*512 + dd];
  int l0 = seg*16;
  for(int l=l0;l<l0+16;l++){
    size_t row = (size_t)rb*128 + l;
    float dtv = dt[row*512 + dd];
    float xcv = xc[row*512 + dd];
    float zgv = xz[row*1024 + 512 + dd];
    const float* dr = dbl + row*48;
    float bx_ = dtv*xcv;
    float y = 0.f;
    #pragma unroll
    for(int s=0;s<16;s++){
      h[s] = __expf(dtv*A[s])*h[s] + bx_*dr[16+s];
      y += h[s]*dr[32+s];
    }
    ybb[row*512 + dd] = f2bf((y + xcv*Dv) * siluf(zgv));
  }
}

// M6 (MFMA) + fused row-LN
__global__ __launch_bounds__(256,2)
void m6_mfma(const bf16* __restrict__ ybb, const bf16* __restrict__ Wout,
             const float* __restrict__ lng, const float* __restrict__ lnb,
             float* __restrict__ mo){
  __shared__ char smem[64*264*4];
  bf16* ybt = (bf16*)smem;
  float* fbuf = (float*)smem;
  int bx = blockIdx.x;
  int lt = bx & 1, b = (bx>>1)&7, r = bx>>4;
  int d = r & 1, rb = r*8 + b;
  size_t rowbase = (size_t)rb*128 + lt*64;
  int t = threadIdx.x;
  for(int i=t;i<4096;i+=256){
    int row = i>>6, c8 = (i&63)*8;
    short8_t v = *(const short8_t*)((const short*)ybb + (rowbase + row)*512 + c8);
    *(short8_t*)&ybt[row*520 + c8] = v;
  }
  __syncthreads();
  int wv = t>>6, lane = t&63, quad = lane>>4, l16 = lane&15;
  int m0 = wv*64;
  f32x4_t acc[4][4];
  #pragma unroll
  for(int ms=0;ms<4;ms++)
    #pragma unroll
    for(int ns=0;ns<4;ns++) acc[ms][ns] = (f32x4_t){0.f,0.f,0.f,0.f};
  const short* wbase = (const short*)Wout + (size_t)d*256*512;
  for(int k0=0;k0<512;k0+=32){
    short8_t afr[4], bfr[4];
    #pragma unroll
    for(int ms=0;ms<4;ms++)
      afr[ms] = *(const short8_t*)(wbase + (size_t)(m0 + ms*16 + l16)*512 + k0 + quad*8);
    #pragma unroll
    for(int ns=0;ns<4;ns++)
      bfr[ns] = *(const short8_t*)&ybt[(ns*16 + l16)*520 + k0 + quad*8];
    #pragma unroll
    for(int ms=0;ms<4;ms++)
      #pragma unroll
      for(int ns=0;ns<4;ns++)
        acc[ms][ns] = __builtin_amdgcn_mfma_f32_16x16x32_bf16(afr[ms], bfr[ns], acc[ms][ns], 0,0,0);
  }
  __syncthreads();
  #pragma unroll
  for(int ns=0;ns<4;ns++){
    int row = ns*16 + l16;
    #pragma unroll
    for(int ms=0;ms<4;ms++){
      int o = m0 + ms*16 + quad*4;
      *(f32x4_t*)(fbuf + row*264 + o) = acc[ms][ns];
    }
  }
  __syncthreads();
  {
    int row = t >> 2, part = t & 3;
    const float* fr = fbuf + row*264;
    float s = 0.f;
    #pragma unroll 8
    for(int j=0;j<64;j++){
      int col = part*64 + ((j + part*16) & 63);
      s += fr[col];
    }
    s += __shfl_xor(s, 1, 64);
    s += __shfl_xor(s, 2, 64);
    float m = s * (1.f/256.f);
    float q = 0.f;
    #pragma unroll 8
    for(int j=0;j<64;j++){
      int col = part*64 + ((j + part*16) & 63);
      float dv = fr[col] - m;
      q += dv*dv;
    }
    q += __shfl_xor(q, 1, 64);
    q += __shfl_xor(q, 2, 64);
    float rs = rsqrtf(q*(1.f/256.f) + EPSV);
    float* dst = mo + (rowbase + row)*256;
    for(int j=0;j<64;j++){
      int col = part*64 + j;
      dst[col] = (fr[col] - m)*rs*lng[col] + lnb[col];
    }
  }
}

// M7 + fused row-LN on outputs
__global__ void m7_proj(const float* __restrict__ mo, const float* __restrict__ PT,
                        const float* __restrict__ pb, const float* __restrict__ lng,
                        const float* __restrict__ lnb, float* __restrict__ resm,
                        float* __restrict__ resn){
  __shared__ float ct[16*512];
  __shared__ float fbuf[16*264];
  int bx = blockIdx.x;
  int tt = bx >> 6, rem = bx & 63, b = rem >> 3, lt = rem & 7;
  int fr_ = tt*2, br = tt*2 + 1;
  for(int i=threadIdx.x;i<16*512;i+=256){
    int lr = i >> 9, k = i & 511;
    int l = lt*16 + lr;
    ct[i] = (k < 256)
      ? mo[(((size_t)(fr_*8+b)*128) + l)*256 + k]
      : mo[(((size_t)(br*8+b)*128) + (127-l))*256 + (k-256)];
  }
  __syncthreads();
  float acc[16];
  #pragma unroll
  for(int q=0;q<16;q++) acc[q] = 0.f;
  int t = threadIdx.x;
  for(int k=0;k<512;k++){
    float pv = PT[(size_t)k*256 + t];
    #pragma unroll
    for(int q=0;q<16;q++) acc[q] += pv * ct[(q<<9) + k];
  }
  float bias = pb[t];
  #pragma unroll
  for(int q=0;q<16;q++) fbuf[q*264 + t] = acc[q] + bias;
  __syncthreads();
  float* dstbuf = tt ? resn : resm;
  if(t < 64){
    int row = t >> 2, part = t & 3;
    const float* fr = fbuf + row*264;
    float s = 0.f;
    for(int j=0;j<64;j++){
      int col = part*64 + ((j + part*16) & 63);
      s += fr[col];
    }
    s += __shfl_xor(s, 1, 64);
    s += __shfl_xor(s, 2, 64);
    float m = s * (1.f/256.f);
    float q = 0.f;
    for(int j=0;j<64;j++){
      int col = part*64 + ((j + part*16) & 63);
      float dv = fr[col] - m;
      q += dv*dv;
    }
    q += __shfl_xor(q, 1, 64);
    q += __shfl_xor(q, 2, 64);
    float rs = rsqrtf(q*(1.f/256.f) + EPSV);
    float* dst = dstbuf + ((size_t)b*128 + lt*16 + row)*256;
    for(int j=0;j<64;j++){
      int col = part*64 + j;
      dst[col] = (fr[col] - m)*rs*lng[col] + lnb[col];
    }
  }
}

// K1: stride-2 transposed depthwise 3x3 + BN + ReLU -> zT (pixel-major bf16)
__global__ __launch_bounds__(256)
void k1_deconv_T(const float* __restrict__ x, const float* __restrict__ wdw,
                 const float* __restrict__ g1, const float* __restrict__ b1,
                 bf16* __restrict__ zT){
  __shared__ float in[2*64*33];
  __shared__ bf16 ot[64*80];
  int bx = blockIdx.x;
  int cb = bx & 3, half = (bx>>2)&1, h = (bx>>3)&127, b = bx>>10;
  int c0 = cb*64, w0 = half*64, iw0 = w0>>1;
  int h_odd = h & 1;
  int ihA = h_odd ? (h-1)>>1 : h>>1;
  int ihB = (h+1)>>1;
  bool hasB = h_odd && (ihB < 64);
  for(int i = threadIdx.x; i < 4224; i += 256){
    int row = i / 2112;
    int rem = i - row*2112;
    int c = rem / 33;
    int iw = rem - c*33;
    int ihl = row ? ihB : ihA;
    bool valid = (iw0 + iw < 64) && (row == 0 || hasB);
    in[i] = valid ? x[(((size_t)b*256 + c0 + c)<<12) + (ihl<<6) + iw0 + iw] : 0.f;
  }
  __syncthreads();
  int c = threadIdx.x & 63, g = threadIdx.x >> 6;
  const float* wp = wdw + (c0+c)*9;
  int khA3 = h_odd ? 6 : 3;
  float wA0 = wp[khA3], wA1 = wp[khA3+1], wA2 = wp[khA3+2];
  float wB0 = wp[0],    wB1 = wp[1],      wB2 = wp[2];
  float scale = g1[c0+c]*BNSC, bias = b1[c0+c];
  const float* inA = in + c*33;
  const float* inB = in + 2112 + c*33;
  #pragma unroll
  for(int i=0;i<16;i++){
    int wi = g*16 + i;
    float s;
    if(!(i&1)){
      int iw = wi>>1;
      s = inA[iw]*wA1 + inB[iw]*wB1;
    } else {
      int iwa = (wi-1)>>1, iwb = (wi+1)>>1;
      s = inA[iwa]*wA2 + inA[iwb]*wA0 + inB[iwa]*wB2 + inB[iwb]*wB0;
    }
    ot[wi*80 + c] = f2bf(fmaxf(s*scale + bias, 0.f));
  }
  __syncthreads();
  int rr = threadIdx.x >> 3;
  int co = (threadIdx.x & 7) * 8;
  size_t obase = (((size_t)b*16384) + (size_t)h*128 + w0)*256 + c0;
  #pragma unroll
  for(int pass=0; pass<2; pass++){
    int wi = rr + pass*32;
    short8_t v = *(const short8_t*)&ot[wi*80 + co];
    *(short8_t*)((short*)zT + obase + (size_t)wi*256 + co) = v;
  }
}

// K2 v3 (restored; measured 59.1us twice): 128-px LDS-staged row tile, 256 thr,
// fused GN1 stats, compact subsampled resS output. grid (128,8).
__global__ __launch_bounds__(256,2)
void k2_mfma(const bf16* __restrict__ zT, const bf16* __restrict__ Wub,
             const float* __restrict__ g2, const float* __restrict__ b2,
             const float* __restrict__ resm, const float* __restrict__ resn,
             bf16* __restrict__ resS, float* __restrict__ gsum1, float* __restrict__ gssq1){
  __shared__ bf16 zt[128*264];
  __shared__ float rm_s[256];
  __shared__ float gn_s[32], gn_q[32];
  int b = blockIdx.y;
  int p0 = blockIdx.x*128;
  int h = p0 >> 7;                 // tile = full row h (w = 0..127)
  int t = threadIdx.x;
  if(t < 32){ gn_s[t] = 0.f; gn_q[t] = 0.f; }
  if(t >= 64 && t < 128){
    int tt = t - 64;
    *(f32x4_t*)&rm_s[tt*4] = *(const f32x4_t*)(resm + ((size_t)b*128 + h)*256 + tt*4);
  }
  {
    const short* src = (const short*)zT + (((size_t)b*16384 + p0)*256);
    int pr = t>>5;
    int cc = (t&31)*8;
    #pragma unroll
    for(int i=0;i<16;i++){
      int p = pr + i*8;
      short8_t v = *(const short8_t*)(src + (size_t)p*256 + cc);
      *(short8_t*)&zt[p*264 + cc] = v;
    }
  }
  __syncthreads();
  int wv = t>>6, lane = t&63, quad = lane>>4, l16 = lane&15;
  int m0 = wv*64;
  f32x4_t acc[4][8];
  #pragma unroll
  for(int ms=0;ms<4;ms++)
    #pragma unroll
    for(int ns=0;ns<8;ns++) acc[ms][ns] = (f32x4_t){0.f,0.f,0.f,0.f};
  const short* wp = (const short*)Wub + (size_t)(m0 + l16)*256 + quad*8;
  short8_t afr[4];
  #pragma unroll
  for(int ms=0;ms<4;ms++) afr[ms] = *(const short8_t*)(wp + (size_t)ms*16*256);
  for(int k0=0;k0<256;k0+=32){
    short8_t anext[4];
    if(k0 + 32 < 256){
      #pragma unroll
      for(int ms=0;ms<4;ms++)
        anext[ms] = *(const short8_t*)(wp + (size_t)ms*16*256 + k0 + 32);
    }
    short8_t bfr[8];
    #pragma unroll
    for(int ns=0;ns<8;ns++)
      bfr[ns] = *(const short8_t*)&zt[(ns*16 + l16)*264 + k0 + quad*8];
    #pragma unroll
    for(int ms=0;ms<4;ms++)
      #pragma unroll
      for(int ns=0;ns<8;ns++)
        acc[ms][ns] = __builtin_amdgcn_mfma_f32_16x16x32_bf16(afr[ms], bfr[ns], acc[ms][ns], 0,0,0);
    #pragma unroll
    for(int ms=0;ms<4;ms++) afr[ms] = anext[ms];
  }
  __syncthreads();   // all waves done reading zt; reuse as output staging tile
  bool h_even = ((h & 1) == 0);
  float sg[4], qg[4];
  #pragma unroll
  for(int ms=0;ms<4;ms++){ sg[ms]=0.f; qg[ms]=0.f; }
  #pragma unroll
  for(int ns=0;ns<8;ns++){
    int pl = ns*16 + l16;            // local pixel = w (0..127)
    const float* rn = resn + ((size_t)b*128 + pl)*256;
    bool store = h_even && ((pl & 1) == 0);
    #pragma unroll
    for(int ms=0;ms<4;ms++){
      int o = m0 + ms*16 + quad*4;
      f32x4_t a = acc[ms][ns];
      f32x4_t gv = *(const f32x4_t*)(g2+o);
      f32x4_t bv = *(const f32x4_t*)(b2+o);
      f32x4_t rmv = *(const f32x4_t*)&rm_s[o];
      f32x4_t rnv = *(const f32x4_t*)(rn+o);
      alignas(8) bf16 ov[4];
      #pragma unroll
      for(int r=0;r<4;r++){
        float zv = a[r]*(gv[r]*BNSC) + bv[r];
        zv = fminf(fmaxf(zv, 0.f), 6.f);
        float gate = fminf(fmaxf(rmv[r]+rnv[r]+3.f, 0.f), 6.f)*(1.f/6.f);
        float vo = zv*gate;
        ov[r] = f2bf(vo);
        sg[ms] += vo;
        qg[ms] += vo*vo;
      }
      if(store) *(short4_t*)&zt[(pl>>1)*264 + o] = *(const short4_t*)ov;
    }
  }
  #pragma unroll
  for(int ms=0;ms<4;ms++){
    float S = sg[ms], Q = qg[ms];
    S += __shfl_xor(S, 1, 64);  Q += __shfl_xor(Q, 1, 64);
    S += __shfl_xor(S, 2, 64);  Q += __shfl_xor(Q, 2, 64);
    S += __shfl_xor(S, 4, 64);  Q += __shfl_xor(Q, 4, 64);
    S += __shfl_xor(S, 8, 64);  Q += __shfl_xor(Q, 8, 64);
    if(l16 == 0){
      int o = m0 + ms*16 + quad*4;   // 4 consecutive channels, same group o>>3
      atomicAdd(&gn_s[o>>3], S);
      atomicAdd(&gn_q[o>>3], Q);
    }
  }
  __syncthreads();
  if(t < 32){
    atomicAdd(&gsum1[b*32 + t], gn_s[t]);
    atomicAdd(&gssq1[b*32 + t], gn_q[t]);
  }
  if(h_even){
    short* dst = (short*)resS + ((size_t)b*4096 + (h>>1)*64)*256;
    #pragma unroll
    for(int it=0; it<8; it++){
      int slot = t + it*256;          // 2048 slots (64 rows x 32)
      int row = slot >> 5;            // ps row 0..63  (w = 2*row)
      int co = (slot & 31)*8;
      short8_t v = *(const short8_t*)&zt[(row)*264 + co];
      *(short8_t*)(dst + (size_t)row*256 + co) = v;
    }
  }
}

// K4 v4 (MFMA): 64-px tile (grid 64x8, ~4 blocks/CU), reads compact resS,
// inline GN1 finalize, per-channel (sum, ssq, cross-with-x) stats.
__global__ __launch_bounds__(256,4)
void k4_mfma(const bf16* __restrict__ resS, const bf16* __restrict__ Wdb,
             const float* __restrict__ gsum1, const float* __restrict__ gssq1,
             const float* __restrict__ gng, const float* __restrict__ gnb,
             const float* __restrict__ dbg, const float* __restrict__ dbb,
             const float* __restrict__ x, float* __restrict__ t1,
             float* __restrict__ t1s, float* __restrict__ t1q, float* __restrict__ t1x){
  __shared__ bf16 at[64*264];
  __shared__ float sc[256], sb[256];
  __shared__ float stm[32], str[32];
  int b = blockIdx.y;
  int q0 = blockIdx.x*64;
  int t = threadIdx.x;
  if(t < 32){
    float m = gsum1[b*32+t] * (1.f/131072.f);
    float var = gssq1[b*32+t] * (1.f/131072.f) - m*m;
    stm[t] = m;
    str[t] = rsqrtf(var + EPSV);
  }
  __syncthreads();
  {
    int cch = t, g = cch>>3;
    float m = stm[g], rs = str[g];
    float s = rs*gng[cch];
    sc[cch] = s; sb[cch] = gnb[cch] - m*s;
  }
  __syncthreads();
  {
    int pr = t>>5;
    int cc = (t&31)*8;
    const short* src = (const short*)resS + ((size_t)b*4096 + q0)*256;
    #pragma unroll
    for(int i=0;i<8;i++){
      int q = pr + i*8;
      short8_t v = *(const short8_t*)(src + (size_t)q*256 + cc);
      const bf16* vv = (const bf16*)&v;
      alignas(16) bf16 ov[8];
      #pragma unroll
      for(int j=0;j<8;j++) ov[j] = f2bf(bf2f(vv[j])*sc[cc+j] + sb[cc+j]);
      *(short8_t*)&at[q*264 + cc] = *(const short8_t*)ov;
    }
  }
  __syncthreads();
  int wv = t>>6, lane = t&63, quad = lane>>4, l16 = lane&15;
  int n0 = wv*64;
  f32x4_t acc[4][4];
  #pragma unroll
  for(int ms=0;ms<4;ms++)
    #pragma unroll
    for(int ns=0;ns<4;ns++) acc[ms][ns] = (f32x4_t){0.f,0.f,0.f,0.f};
  const short* wp = (const short*)Wdb + (size_t)(n0 + l16)*256 + quad*8;
  short8_t bfr[4];
  #pragma unroll
  for(int ns=0;ns<4;ns++) bfr[ns] = *(const short8_t*)(wp + (size_t)ns*16*256);
  for(int k0=0;k0<256;k0+=32){
    short8_t bnext[4];
    if(k0 + 32 < 256){
      #pragma unroll
      for(int ns=0;ns<4;ns++)
        bnext[ns] = *(const short8_t*)(wp + (size_t)ns*16*256 + k0 + 32);
    }
    short8_t afr[4];
    #pragma unroll
    for(int ms=0;ms<4;ms++)
      afr[ms] = *(const short8_t*)&at[(ms*16 + l16)*264 + k0 + quad*8];
    #pragma unroll
    for(int ms=0;ms<4;ms++)
      #pragma unroll
      for(int ns=0;ns<4;ns++)
        acc[ms][ns] = __builtin_amdgcn_mfma_f32_16x16x32_bf16(afr[ms], bfr[ns], acc[ms][ns], 0,0,0);
    #pragma unroll
    for(int ns=0;ns<4;ns++) bfr[ns] = bnext[ns];
  }
  #pragma unroll
  for(int ns=0;ns<4;ns++){
    int o = n0 + ns*16 + l16;
    float s2 = dbg[o]*BNSC, bb2 = dbb[o];
    float* dst = t1 + (((size_t)b*256 + o) << 12);
    const float* xsrc = x + (((size_t)b*256 + o) << 12);
    float s_=0.f, q_=0.f, c_=0.f;
    #pragma unroll
    for(int ms=0;ms<4;ms++){
      int ps = q0 + ms*16 + quad*4;
      f32x4_t a = acc[ms][ns];
      f32x4_t xv = *(const f32x4_t*)(xsrc + ps);
      f32x4_t ov;
      #pragma unroll
      for(int r=0;r<4;r++){
        ov[r] = a[r]*s2 + bb2;
        s_ += ov[r];
        q_ += ov[r]*ov[r];
        c_ += ov[r]*xv[r];
      }
      *(f32x4_t*)(dst + ps) = ov;
    }
    s_ += __shfl_xor(s_, 16, 64);
    q_ += __shfl_xor(q_, 16, 64);
    c_ += __shfl_xor(c_, 16, 64);
    s_ += __shfl_xor(s_, 32, 64);
    q_ += __shfl_xor(q_, 32, 64);
    c_ += __shfl_xor(c_, 32, 64);
    if(quad == 0){
      atomicAdd(&t1s[b*256 + o], s_);
      atomicAdd(&t1q[b*256 + o], q_);
      atomicAdd(&t1x[b*256 + o], c_);
    }
  }
}

// K8 v3 (float4): folds compose_gn per block (each block = single (b,c));
// out = A*t1 + B*x + C  where A/B/C derive from GN2/GN3 affine composition.
__global__ void k8_gn_out(const float* __restrict__ t1, const float* __restrict__ x,
                          const float* __restrict__ t1s, const float* __restrict__ t1q,
                          const float* __restrict__ t1x, const float* __restrict__ xs,
                          const float* __restrict__ xq, const float* __restrict__ gng,
                          const float* __restrict__ gnb, float* __restrict__ out){
  int i4 = blockIdx.x*256 + threadIdx.x;
  int idx = i4 << 2;
  int c = (idx >> 12) & 255, b = idx >> 20;
  int base = b*256 + (c & ~7);     // stats base for this channel group
  int cb0 = c & ~7;
  // GN2 group stats
  float gs = 0.f, gq = 0.f;
  #pragma unroll
  for(int j=0;j<8;j++){ gs += t1s[base+j]; gq += t1q[base+j]; }
  float m2 = gs*(1.f/32768.f);
  float v2 = gq*(1.f/32768.f) - m2*m2;
  float rs2 = rsqrtf(v2 + EPSV);
  // GN3 group stats of u = a_j*t1_j + bb_j + x_j summed over group channels
  float gSu = 0.f, gQu = 0.f;
  #pragma unroll
  for(int j=0;j<8;j++){
    float ts = t1s[base+j], tq = t1q[base+j], tx = t1x[base+j];
    float sx = xs[base+j],  qx = xq[base+j];
    float a  = rs2*gng[cb0+j];
    float bb = gnb[cb0+j] - m2*a;
    gSu += a*ts + 4096.f*bb + sx;
    gQu += a*a*tq + 4096.f*bb*bb + qx + 2.f*a*bb*ts + 2.f*a*tx + 2.f*bb*sx;
  }
  float m3 = gSu*(1.f/32768.f);
  float v3 = gQu*(1.f/32768.f) - m3*m3;
  float rs3 = rsqrtf(v3 + EPSV);
  float s3 = rs3*gng[c];
  float a_c  = rs2*gng[c];
  float bb_c = gnb[c] - m2*a_c;
  float A = a_c*s3, Bv = s3, C = (bb_c - m3)*s3 + gnb[c];
  f32x4_t tv = *(const f32x4_t*)(t1 + idx);
  f32x4_t xv = *(const f32x4_t*)(x + idx);
  f32x4_t ov;
  #pragma unroll
  for(int r=0;r<4;r++) ov[r] = A*tv[r] + Bv*xv[r] + C;
  *(f32x4_t*)(out + idx) = ov;
}

extern "C" void kernel_launch(void* const* d_in, const int* in_sizes, int n_in,
                              void* d_out, int out_size, void* d_ws, size_t ws_size,
                              hipStream_t stream){
  const float* x      = (const float*)d_in[0];
  const float* pos    = (const float*)d_in[1];
  const float* ln_g   = (const float*)d_in[2];
  const float* ln_b   = (const float*)d_in[3];
  const float* in_w   = (const float*)d_in[4];
  const float* conv_w = (const float*)d_in[5];
  const float* conv_b = (const float*)d_in[6];
  const float* xproj  = (const float*)d_in[7];
  const float* dt_w   = (const float*)d_in[8];
  const float* dt_b   = (const float*)d_in[9];
  const float* A_log  = (const float*)d_in[10];
  const float* Dp     = (const float*)d_in[11];
  const float* out_w  = (const float*)d_in[12];
  const float* proj_w = (const float*)d_in[13];
  const float* proj_b = (const float*)d_in[14];
  const float* dw_w   = (const float*)d_in[15];
  const float* bn1g   = (const float*)d_in[16];
  const float* bn1b   = (const float*)d_in[17];
  const float* pw_w   = (const float*)d_in[18];
  const float* bn2g   = (const float*)d_in[19];
  const float* bn2b   = (const float*)d_in[20];
  const float* dpw_w  = (const float*)d_in[21];
  const float* dbng   = (const float*)d_in[22];
  const float* dbnb   = (const float*)d_in[23];
  const float* gng    = (const float*)d_in[24];
  const float* gnb    = (const float*)d_in[25];
  float* out = (float*)d_out;

  float* ws = (float*)d_ws;
  bf16*  resS = (bf16*)ws;                       // compact subsampled (b,4096,256), 16MB
  bf16*  zT   = (bf16*)(ws + 16777216);          // pixel-major (b,p,c), 64MB
  float* scanP = ws + 16777216;                  // overlay of zT region
  float* scanH = ws + 16777216 + 2097152;
  float* zone = ws + 33554432;
  float* xz   = zone;                            // 4,194,304
  float* xc   = xz  + 4194304;                   // 2,097,152
  float* dbl  = xc  + 2097152;                   //   196,608
  float* dtb  = dbl + 196608;                    // 2,097,152
  bf16*  ybb  = (bf16*)(dtb + 2097152);          // 1,048,576 f worth
  bf16*  xcb  = (bf16*)(dtb + 2097152 + 524288); // 1,048,576 f worth (2M bf16)
  float* t1   = zone;                            // overlay (first 8,388,608)
  float* mo   = zone + 9633792;                  // 1,048,576
  float* resm = mo   + 1048576;
  float* resn = resm + 262144;
  float* pmax = resn + 262144;
  float* pmin = pmax + 262144;
  float* PT   = pmin + 262144;
  bf16*  ubmax= (bf16*)(PT + 131072);
  bf16*  ubmin= (bf16*)(PT + 131072 + 131072);
  bf16*  Winb = (bf16*)(PT + 131072 + 262144);
  bf16*  Woutb= (bf16*)(PT + 131072 + 524288);
  bf16*  Wub  = (bf16*)(PT + 131072 + 655360);
  bf16*  Wdb  = (bf16*)(PT + 131072 + 688128);
  bf16*  Wxpb = (bf16*)(PT + 131072 + 720896);   // 49152 bf16 = 24576 floats
  float* gacc = PT + 131072 + 745472;
  float* gsum1 = gacc,        *gssq1 = gacc + 256;
  float* t1s = gacc + 512;
  float* t1q = gacc + 2560;
  float* t1x = gacc + 4608;
  float* xs  = gacc + 6656;
  float* xq  = gacc + 8704;

  prep_weights<<<4288,256,0,stream>>>(in_w, out_w, pw_w, dpw_w, proj_w, xproj,
                                      Winb, Woutb, Wub, Wdb, Wxpb, PT, gacc);

  r1_reduce_pe<<<2048,256,0,stream>>>(x, pos, pmax, pmin, xs, xq);
  ln_rows2<<<2048,256,0,stream>>>(pmax, pmin, ln_g, ln_b, ubmax, ubmin);

  m1_mfma<<<256,256,0,stream>>>(ubmax, ubmin, Winb, xz);
  m2_conv<<<2048,256,0,stream>>>(xz, conv_w, conv_b, xc, xcb);
  m3_xproj<<<64,256,0,stream>>>(xcb, Wxpb, dbl);
  m4_dt<<<2048,256,0,stream>>>(dbl, dt_w, dt_b, dtb);
  m5_passA<<<512,256,0,stream>>>(dtb, xc, dbl, A_log, scanP, scanH);
  m5_passB<<<512,256,0,stream>>>(dtb, xc, dbl, xz, A_log, Dp, scanP, scanH, ybb);
  m6_mfma<<<64,256,0,stream>>>(ybb, Woutb, ln_g, ln_b, mo);
  m7_proj<<<128,256,0,stream>>>(mo, PT, proj_b, ln_g, ln_b, resm, resn);

  k1_deconv_T<<<8192,256,0,stream>>>(x, dw_w, bn1g, bn1b, zT);
  k2_mfma<<<dim3(128,8),256,0,stream>>>(zT, Wub, bn2g, bn2b, resm, resn, resS,
                                        gsum1, gssq1);

  k4_mfma<<<dim3(64,8),256,0,stream>>>(resS, Wdb, gsum1, gssq1,
                                       gng, gnb, dbng, dbnb, x, t1, t1s, t1q, t1x);

  k8_gn_out<<<8192,256,0,stream>>>(t1, x, t1s, t1q, t1x, xs, xq, gng, gnb, out);
}